// Round 5
// baseline (345.133 us; speedup 1.0000x reference)
//
#include <hip/hip_runtime.h>

// Problem constants
constexpr int B  = 16;
constexpr int LT = 512;
constexpr int D  = 1024;
constexpr int N  = 4096;
constexpr int H  = 16;
constexpr int DH = D / H;       // 64
constexpr int LMAX = N / B;     // 256
constexpr float LN_EPS = 1e-5f;

typedef short  s16x8 __attribute__((ext_vector_type(8)));
typedef float  f32x4 __attribute__((ext_vector_type(4)));

__device__ __forceinline__ unsigned short f2bf(float x) {
    unsigned int u = __float_as_uint(x);
    unsigned int r = (u + 0x7fffu + ((u >> 16) & 1u)) >> 16;   // RNE
    return (unsigned short)r;
}
__device__ __forceinline__ float bf2f(unsigned short u) {
    return __uint_as_float((unsigned int)u << 16);
}

__device__ __forceinline__ void load_lds16(const void* g, void* l) {
    __builtin_amdgcn_global_load_lds(
        (const __attribute__((address_space(1))) unsigned int*)g,
        (__attribute__((address_space(3))) unsigned int*)l, 16, 0, 0);
}

// ---------------------------------------------------------------------------
__global__ void prep_kernel(const int* __restrict__ sb, int* __restrict__ counts,
                            int* __restrict__ starts, int* __restrict__ pos) {
    __shared__ int s_counts[B], s_starts[B];
    int t = threadIdx.x;
    if (t < B) s_counts[t] = 0;
    __syncthreads();
    for (int i = t; i < N; i += 256) atomicAdd(&s_counts[sb[i]], 1);
    __syncthreads();
    if (t == 0) {
        int run = 0;
        for (int b = 0; b < B; b++) { s_starts[b] = run; run += s_counts[b]; }
    }
    __syncthreads();
    if (t < B) { counts[t] = s_counts[t]; starts[t] = s_starts[t]; }
    for (int i = t; i < N; i += 256) {
        int b = sb[i];
        pos[i] = i - s_starts[b];
    }
}

// ---------------------------------------------------------------------------
__global__ void scatter_kernel(const float* __restrict__ st, const int* __restrict__ sb,
                               const int* __restrict__ pos, unsigned short* __restrict__ padded) {
    int i = blockIdx.x;
    int b = sb[i], p = pos[i];
    int d = threadIdx.x * 4;
    float4 v = *(const float4*)&st[(size_t)i * D + d];
    ushort4 o;
    o.x = f2bf(v.x); o.y = f2bf(v.y); o.z = f2bf(v.z); o.w = f2bf(v.w);
    *(ushort4*)&padded[((size_t)(b * LMAX + p)) * D + d] = o;
}

// fused fp32->bf16 cast of three regions
__global__ __launch_bounds__(256) void cast3_kernel(
        const float* __restrict__ x0, unsigned short* __restrict__ y0, int n0,
        const float* __restrict__ x1, unsigned short* __restrict__ y1, int n1,
        const float* __restrict__ x2, unsigned short* __restrict__ y2, int n2) {
    long long i = (long long)(blockIdx.x * 256 + threadIdx.x) * 8;
    const float* x; unsigned short* y;
    if (i < n0)                { x = x0 + i; y = y0 + i; }
    else if (i < (long long)n0 + n1) { long long j = i - n0; x = x1 + j; y = y1 + j; }
    else if (i < (long long)n0 + n1 + n2) { long long j = i - n0 - n1; x = x2 + j; y = y2 + j; }
    else return;
    float4 a = *(const float4*)x;
    float4 b = *(const float4*)(x + 4);
    ushort4 o1, o2;
    o1.x = f2bf(a.x); o1.y = f2bf(a.y); o1.z = f2bf(a.z); o1.w = f2bf(a.w);
    o2.x = f2bf(b.x); o2.y = f2bf(b.y); o2.z = f2bf(b.z); o2.w = f2bf(b.w);
    *(ushort4*)y = o1;
    *(ushort4*)(y + 4) = o2;
}

// ---------------------------------------------------------------------------
// GEMM tile body: C[m0:+128, n0:+128] = A @ W^T + bias. BK=64 as two 32-wide
// panels per barrier pair (halves barrier count vs m97; per-panel layout
// [128][32] keeps the frag-read bank pattern unchanged).
constexpr int PANEL = 128 * 32;

template<typename OutT, bool BIAS_ROW>
__device__ __forceinline__ void gemm_tile(const unsigned short* __restrict__ A,
                                          const unsigned short* __restrict__ W,
                                          const float* __restrict__ bias,
                                          OutT* __restrict__ C,
                                          int Nn, int K, int m0, int n0,
                                          unsigned short* As, unsigned short* Bs) {
    const int tid  = threadIdx.x;
    const int lane = tid & 63;
    const int wave = tid >> 6;
    const int wm = (wave >> 1) * 64, wn = (wave & 1) * 64;

    const int srow = tid >> 2;
    const int scol = (tid & 3) * 8;
    const unsigned short* Ag = A + (size_t)(m0 + srow) * K + scol;
    const unsigned short* Wg = W + (size_t)(n0 + srow) * K + scol;
    unsigned short* Asl = As + tid * 8;
    unsigned short* Bsl = Bs + tid * 8;

    const int fm = lane & 15;
    const int fk = (lane >> 4) * 8;

    f32x4 acc[4][4];
#pragma unroll
    for (int i = 0; i < 4; i++)
#pragma unroll
        for (int j = 0; j < 4; j++) acc[i][j] = (f32x4){0.f, 0.f, 0.f, 0.f};

    for (int k0 = 0; k0 < K; k0 += 64) {
        __syncthreads();
        // panel 0: cols [k0, k0+32)
        load_lds16(Ag + k0, Asl);
        load_lds16(Ag + (size_t)64 * K + k0, Asl + 64 * 32);
        load_lds16(Wg + k0, Bsl);
        load_lds16(Wg + (size_t)64 * K + k0, Bsl + 64 * 32);
        // panel 1: cols [k0+32, k0+64)
        load_lds16(Ag + k0 + 32, Asl + PANEL);
        load_lds16(Ag + (size_t)64 * K + k0 + 32, Asl + PANEL + 64 * 32);
        load_lds16(Wg + k0 + 32, Bsl + PANEL);
        load_lds16(Wg + (size_t)64 * K + k0 + 32, Bsl + PANEL + 64 * 32);
        __syncthreads();

#pragma unroll
        for (int hp = 0; hp < 2; hp++) {
            const unsigned short* Ap = As + hp * PANEL;
            const unsigned short* Bp = Bs + hp * PANEL;
            s16x8 af[4], bf[4];
#pragma unroll
            for (int i = 0; i < 4; i++) {
                af[i] = *(const s16x8*)&Ap[(wm + i * 16 + fm) * 32 + fk];
                bf[i] = *(const s16x8*)&Bp[(wn + i * 16 + fm) * 32 + fk];
            }
#pragma unroll
            for (int i = 0; i < 4; i++)
#pragma unroll
                for (int j = 0; j < 4; j++)
                    acc[i][j] = __builtin_amdgcn_mfma_f32_16x16x32_bf16(af[i], bf[j], acc[i][j], 0, 0, 0);
        }
    }

    const int fr = (lane >> 4) * 4;
#pragma unroll
    for (int j = 0; j < 4; j++) {
        int col = n0 + wn + j * 16 + fm;
        float bc = BIAS_ROW ? 0.f : bias[col];
#pragma unroll
        for (int i = 0; i < 4; i++) {
            size_t rbase = (size_t)(m0 + wm + i * 16 + fr) * Nn + col;
#pragma unroll
            for (int r = 0; r < 4; r++) {
                float val = acc[i][j][r] + (BIAS_ROW ? bias[m0 + wm + i * 16 + fr + r] : bc);
                if constexpr (sizeof(OutT) == 2)
                    C[rbase + (size_t)r * Nn] = (OutT)f2bf(val);
                else
                    C[rbase + (size_t)r * Nn] = (OutT)val;
            }
        }
    }
}

// Fused QKV: flat grid of 1280 blocks. [0,256)=Q, [256,768)=K, [768,1280)=V^T.
__global__ __launch_bounds__(256) void qkv_fused(const unsigned short* __restrict__ padded,
                                                 const unsigned short* __restrict__ text,
                                                 const unsigned short* __restrict__ wqkv,
                                                 const float* __restrict__ bqkv,
                                                 unsigned short* __restrict__ qb,
                                                 unsigned short* __restrict__ kb,
                                                 unsigned short* __restrict__ vtb) {
    __shared__ __align__(16) unsigned short As[2 * PANEL];
    __shared__ __align__(16) unsigned short Bs[2 * PANEL];
    int flat = blockIdx.x;
    if (flat < 256) {
        gemm_tile<unsigned short, false>(padded, wqkv, bqkv, qb,
                                         D, D, (flat >> 3) * 128, (flat & 7) * 128, As, Bs);
    } else if (flat < 768) {
        int f = flat - 256;
        gemm_tile<unsigned short, false>(text, wqkv + (size_t)D * D, bqkv + D, kb,
                                         D, D, (f >> 3) * 128, (f & 7) * 128, As, Bs);
    } else {
        int f = flat - 768;   // V^T: A=wv rows (M=1024), W=text (Nn=8192), bias by row
        gemm_tile<unsigned short, true>(wqkv + 2 * (size_t)D * D, text, bqkv + 2 * D, vtb,
                                        B * LT, D, (f >> 6) * 128, (f & 63) * 128, As, Bs);
    }
}

// attn_out GEMM, bf16 out
__global__ __launch_bounds__(256) void gemm_bf(const unsigned short* __restrict__ A,
                                               const unsigned short* __restrict__ W,
                                               const float* __restrict__ bias,
                                               unsigned short* __restrict__ C, int Nn, int K) {
    __shared__ __align__(16) unsigned short As[2 * PANEL];
    __shared__ __align__(16) unsigned short Bs[2 * PANEL];
    gemm_tile<unsigned short, false>(A, W, bias, C, Nn, K,
                                     blockIdx.y * 128, blockIdx.x * 128, As, Bs);
}

// ---------------------------------------------------------------------------
// MFMA attention, barrier-light: K and V^T B-fragments are lane-contiguous
// 16B in global memory -> load directly, no LDS staging. Only P's C->A
// layout transform round-trips through per-wave LDS.
__global__ __launch_bounds__(256) void attn_mfma(const unsigned short* __restrict__ qb,
                                                 const unsigned short* __restrict__ kb,
                                                 const unsigned short* __restrict__ vtb,
                                                 unsigned short* __restrict__ ctx) {
    __shared__ __align__(16) unsigned short Ps[4 * 16 * 136];  // per-wave P chunk [16][136]

    const int tid = threadIdx.x;
    const int lane = tid & 63;
    const int wv = tid >> 6;
    const int fm = lane & 15;
    const int quad = lane >> 4;
    const int b = blockIdx.z, h = blockIdx.y;
    const int q0 = blockIdx.x * 64 + wv * 16;

    const size_t qrow = (size_t)(b * LMAX + q0 + fm) * D + h * DH;
    const s16x8 aq0 = *(const s16x8*)&qb[qrow + quad * 8];
    const s16x8 aq1 = *(const s16x8*)&qb[qrow + 32 + quad * 8];

    // ---- pass 1: scores, B-frags straight from global ----
    f32x4 sc[32];
    const unsigned short* kr = kb + (size_t)(b * LT) * D + h * DH + (size_t)fm * D + quad * 8;
#pragma unroll
    for (int t = 0; t < 32; t++) {
        s16x8 bk0 = *(const s16x8*)kr;
        s16x8 bk1 = *(const s16x8*)(kr + 32);
        f32x4 a = (f32x4){0.f, 0.f, 0.f, 0.f};
        a = __builtin_amdgcn_mfma_f32_16x16x32_bf16(aq0, bk0, a, 0, 0, 0);
        a = __builtin_amdgcn_mfma_f32_16x16x32_bf16(aq1, bk1, a, 0, 0, 0);
        sc[t] = a;
        kr += 16 * D;
    }

    // ---- softmax in registers (row q = quad*4+r lives on this quad's 16 lanes) ----
    const float scale = 0.125f;
    float mx[4], l[4], inv[4];
#pragma unroll
    for (int r = 0; r < 4; r++) {
        float m = sc[0][r];
#pragma unroll
        for (int t = 1; t < 32; t++) m = fmaxf(m, sc[t][r]);
        mx[r] = m;
    }
#pragma unroll
    for (int o = 1; o < 16; o <<= 1)
#pragma unroll
        for (int r = 0; r < 4; r++) mx[r] = fmaxf(mx[r], __shfl_xor(mx[r], o));
#pragma unroll
    for (int r = 0; r < 4; r++) l[r] = 0.f;
#pragma unroll
    for (int t = 0; t < 32; t++)
#pragma unroll
        for (int r = 0; r < 4; r++) {
            float e = __expf((sc[t][r] - mx[r]) * scale);
            sc[t][r] = e;
            l[r] += e;
        }
#pragma unroll
    for (int o = 1; o < 16; o <<= 1)
#pragma unroll
        for (int r = 0; r < 4; r++) l[r] += __shfl_xor(l[r], o);
#pragma unroll
    for (int r = 0; r < 4; r++) inv[r] = 1.f / l[r];

    // ---- pass 2: ctx = P @ V, V^T frags straight from global ----
    f32x4 co[4];
#pragma unroll
    for (int n = 0; n < 4; n++) co[n] = (f32x4){0.f, 0.f, 0.f, 0.f};
    unsigned short* Pw = Ps + wv * (16 * 136);
    const unsigned short* vr0 = vtb + (size_t)(h * DH) * (B * LT) + (size_t)b * LT
                                    + (size_t)fm * (B * LT) + quad * 8;

    for (int c = 0; c < 4; c++) {
        // write this wave's P chunk (C-layout regs -> [q][key] bf16); wave-local LDS
#pragma unroll
        for (int t = 0; t < 8; t++)
#pragma unroll
            for (int r = 0; r < 4; r++)
                Pw[(quad * 4 + r) * 136 + t * 16 + fm] = f2bf(sc[c * 8 + t][r]);
        __syncthreads();   // conservative wave-convergence / LDS ordering point
#pragma unroll
        for (int s = 0; s < 4; s++) {
            s16x8 ap = *(const s16x8*)&Pw[fm * 136 + s * 32 + quad * 8];
#pragma unroll
            for (int n = 0; n < 4; n++) {
                s16x8 bv = *(const s16x8*)(vr0 + (size_t)(n * 16) * (B * LT) + c * 128 + s * 32);
                co[n] = __builtin_amdgcn_mfma_f32_16x16x32_bf16(ap, bv, co[n], 0, 0, 0);
            }
        }
        __syncthreads();
    }

    const size_t obase = (size_t)(b * LMAX + q0) * D + h * DH;
#pragma unroll
    for (int n = 0; n < 4; n++)
#pragma unroll
        for (int r = 0; r < 4; r++)
            ctx[obase + (size_t)(quad * 4 + r) * D + n * 16 + fm] = f2bf(co[n][r] * inv[r]);
}

// ---------------------------------------------------------------------------
// Fused LayerNorm + segment-mean partial (bf16 input rows).
__global__ __launch_bounds__(256) void lnmean_kernel(const unsigned short* __restrict__ f1,
                                                     const float* __restrict__ g,
                                                     const float* __restrict__ bb,
                                                     const int* __restrict__ counts,
                                                     float* __restrict__ msum) {
    int b = blockIdx.x;
    int cnt = counts[b];
    int s0 = blockIdx.y * 32;
    int s1 = min(cnt, s0 + 32);
    if (s0 >= s1) return;
    int t = threadIdx.x;
    int wv = t >> 6, ln = t & 63;
    float4 gg = ((const float4*)g)[t];
    float4 bv = ((const float4*)bb)[t];
    float acc[4] = {0.f, 0.f, 0.f, 0.f};
    __shared__ float red[8];

    for (int s = s0; s < s1; s++) {
        const unsigned short* x = f1 + ((size_t)(b * LMAX + s)) * D;
        ushort4 u = ((const ushort4*)x)[t];
        float4 val = {bf2f(u.x), bf2f(u.y), bf2f(u.z), bf2f(u.w)};
        float sm = val.x + val.y + val.z + val.w;
        float ss = val.x * val.x + val.y * val.y + val.z * val.z + val.w * val.w;
#pragma unroll
        for (int o = 32; o; o >>= 1) { sm += __shfl_xor(sm, o); ss += __shfl_xor(ss, o); }
        if (ln == 0) { red[wv] = sm; red[4 + wv] = ss; }
        __syncthreads();
        sm = red[0] + red[1] + red[2] + red[3];
        ss = red[4] + red[5] + red[6] + red[7];
        __syncthreads();
        float mu = sm * (1.f / D);
        float var = ss * (1.f / D) - mu * mu;
        float r = rsqrtf(var + LN_EPS);
        acc[0] += (val.x - mu) * r * gg.x + bv.x;
        acc[1] += (val.y - mu) * r * gg.y + bv.y;
        acc[2] += (val.z - mu) * r * gg.z + bv.z;
        acc[3] += (val.w - mu) * r * gg.w + bv.w;
    }
    float inv = 1.f / (float)max(cnt, 1);
#pragma unroll
    for (int j = 0; j < 4; j++)
        atomicAdd(&msum[(size_t)b * D + t * 4 + j], acc[j] * inv);
}

// Mini projection: out[b][n] = msum[b] . proj_w[n] + bias[n]  (fp32).
__global__ __launch_bounds__(256) void tproj_kernel(const float* __restrict__ msum,
                                                    const float* __restrict__ W,
                                                    const float* __restrict__ bias,
                                                    float* __restrict__ out) {
    int lane = threadIdx.x & 63;
    int n = blockIdx.x * 4 + (threadIdx.x >> 6);
    float4 wr[4];
#pragma unroll
    for (int i = 0; i < 4; i++)
        wr[i] = *(const float4*)&W[(size_t)n * D + i * 256 + lane * 4];
    float bn = bias[n];
    for (int b = 0; b < B; b++) {
        float s = 0.f;
#pragma unroll
        for (int i = 0; i < 4; i++) {
            float4 m4 = *(const float4*)&msum[(size_t)b * D + i * 256 + lane * 4];
            s += m4.x * wr[i].x + m4.y * wr[i].y + m4.z * wr[i].z + m4.w * wr[i].w;
        }
#pragma unroll
        for (int o = 32; o; o >>= 1) s += __shfl_xor(s, o);
        if (lane == 0) out[(size_t)b * D + n] = s + bn;
    }
}

// ---------------------------------------------------------------------------
extern "C" void kernel_launch(void* const* d_in, const int* in_sizes, int n_in,
                              void* d_out, int out_size, void* d_ws, size_t ws_size,
                              hipStream_t stream) {
    const float* struct_token = (const float*)d_in[0];
    const float* text_token   = (const float*)d_in[1];
    const float* in_proj_w    = (const float*)d_in[2];
    const float* in_proj_b    = (const float*)d_in[3];
    const float* attn_out_w   = (const float*)d_in[4];
    const float* attn_out_b   = (const float*)d_in[5];
    const float* ln_g         = (const float*)d_in[6];
    const float* ln_b         = (const float*)d_in[7];
    const float* proj_w       = (const float*)d_in[8];
    const float* proj_b       = (const float*)d_in[9];
    const int*   sb           = (const int*)d_in[10];
    float* out = (float*)d_out;

    const size_t MQ  = (size_t)B * LMAX;     // 4096
    const size_t MKV = (size_t)B * LT;       // 8192

    char* p = (char*)d_ws;
    unsigned short* padded_b = (unsigned short*)p;  p += MQ * D * 2;
    unsigned short* text_b   = (unsigned short*)p;  p += MKV * D * 2;
    unsigned short* wqkv_b   = (unsigned short*)p;  p += (size_t)3 * D * D * 2;
    unsigned short* wattn_b  = (unsigned short*)p;  p += (size_t)D * D * 2;
    unsigned short* qb       = (unsigned short*)p;  p += MQ * D * 2;
    unsigned short* kb       = (unsigned short*)p;  p += MKV * D * 2;
    unsigned short* vtb      = (unsigned short*)p;  p += MKV * D * 2;   // [D][MKV]
    unsigned short* ctx_b    = (unsigned short*)p;  p += MQ * D * 2;
    unsigned short* f1b      = (unsigned short*)p;  p += MQ * D * 2;
    float* msum = (float*)p;  p += (size_t)B * D * 4;
    int* pos    = (int*)p;  p += N * 4;
    int* counts = (int*)p;  p += B * 4;
    int* starts = (int*)p;  p += B * 4;

    hipMemsetAsync(padded_b, 0, MQ * D * 2, stream);
    hipMemsetAsync(msum, 0, (size_t)B * D * 4, stream);
    prep_kernel<<<1, 256, 0, stream>>>(sb, counts, starts, pos);
    scatter_kernel<<<N, 256, 0, stream>>>(struct_token, sb, pos, padded_b);

    cast3_kernel<<<6144, 256, 0, stream>>>(
        text_token, text_b, (int)(MKV * D),
        in_proj_w,  wqkv_b, 3 * D * D,
        attn_out_w, wattn_b, D * D);

    qkv_fused<<<1280, 256, 0, stream>>>(padded_b, text_b, wqkv_b, in_proj_b, qb, kb, vtb);

    attn_mfma<<<dim3(LMAX / 64, H, B), 256, 0, stream>>>(qb, kb, vtb, ctx_b);

    gemm_bf<<<dim3(D / 128, MQ / 128), 256, 0, stream>>>(ctx_b, wattn_b, attn_out_b, f1b, D, D);

    lnmean_kernel<<<dim3(B, LMAX / 32), 256, 0, stream>>>(f1b, ln_g, ln_b, counts, msum);

    tproj_kernel<<<256, 256, 0, stream>>>(msum, proj_w, proj_b, out);
}

// Round 6
// 307.355 us; speedup vs baseline: 1.1229x; 1.1229x over previous
//
#include <hip/hip_runtime.h>

// Problem constants
constexpr int B  = 16;
constexpr int LT = 512;
constexpr int D  = 1024;
constexpr int N  = 4096;
constexpr int H  = 16;
constexpr int DH = D / H;       // 64
constexpr int LMAX = N / B;     // 256
constexpr float LN_EPS = 1e-5f;

typedef short  s16x8 __attribute__((ext_vector_type(8)));
typedef float  f32x4 __attribute__((ext_vector_type(4)));

__device__ __forceinline__ unsigned short f2bf(float x) {
    unsigned int u = __float_as_uint(x);
    unsigned int r = (u + 0x7fffu + ((u >> 16) & 1u)) >> 16;   // RNE
    return (unsigned short)r;
}
__device__ __forceinline__ float bf2f(unsigned short u) {
    return __uint_as_float((unsigned int)u << 16);
}

__device__ __forceinline__ void load_lds16(const void* g, void* l) {
    __builtin_amdgcn_global_load_lds(
        (const __attribute__((address_space(1))) unsigned int*)g,
        (__attribute__((address_space(3))) unsigned int*)l, 16, 0, 0);
}

// ---------------------------------------------------------------------------
__global__ void prep_kernel(const int* __restrict__ sb, int* __restrict__ counts,
                            int* __restrict__ starts, int* __restrict__ pos) {
    __shared__ int s_counts[B], s_starts[B];
    int t = threadIdx.x;
    if (t < B) s_counts[t] = 0;
    __syncthreads();
    for (int i = t; i < N; i += 256) atomicAdd(&s_counts[sb[i]], 1);
    __syncthreads();
    if (t == 0) {
        int run = 0;
        for (int b = 0; b < B; b++) { s_starts[b] = run; run += s_counts[b]; }
    }
    __syncthreads();
    if (t < B) { counts[t] = s_counts[t]; starts[t] = s_starts[t]; }
    for (int i = t; i < N; i += 256) {
        int b = sb[i];
        pos[i] = i - s_starts[b];
    }
}

// ---------------------------------------------------------------------------
__global__ void scatter_kernel(const float* __restrict__ st, const int* __restrict__ sb,
                               const int* __restrict__ pos, unsigned short* __restrict__ padded) {
    int i = blockIdx.x;
    int b = sb[i], p = pos[i];
    int d = threadIdx.x * 4;
    float4 v = *(const float4*)&st[(size_t)i * D + d];
    ushort4 o;
    o.x = f2bf(v.x); o.y = f2bf(v.y); o.z = f2bf(v.z); o.w = f2bf(v.w);
    *(ushort4*)&padded[((size_t)(b * LMAX + p)) * D + d] = o;
}

// fused fp32->bf16 cast of three regions
__global__ __launch_bounds__(256) void cast3_kernel(
        const float* __restrict__ x0, unsigned short* __restrict__ y0, int n0,
        const float* __restrict__ x1, unsigned short* __restrict__ y1, int n1,
        const float* __restrict__ x2, unsigned short* __restrict__ y2, int n2) {
    long long i = (long long)(blockIdx.x * 256 + threadIdx.x) * 8;
    const float* x; unsigned short* y;
    if (i < n0)                { x = x0 + i; y = y0 + i; }
    else if (i < (long long)n0 + n1) { long long j = i - n0; x = x1 + j; y = y1 + j; }
    else if (i < (long long)n0 + n1 + n2) { long long j = i - n0 - n1; x = x2 + j; y = y2 + j; }
    else return;
    float4 a = *(const float4*)x;
    float4 b = *(const float4*)(x + 4);
    ushort4 o1, o2;
    o1.x = f2bf(a.x); o1.y = f2bf(a.y); o1.z = f2bf(a.z); o1.w = f2bf(a.w);
    o2.x = f2bf(b.x); o2.y = f2bf(b.y); o2.z = f2bf(b.z); o2.w = f2bf(b.w);
    *(ushort4*)y = o1;
    *(ushort4*)(y + 4) = o2;
}

// ---------------------------------------------------------------------------
// GEMM tile body with custom epilogue. C tile = A[m0:+128,:K] @ W[n0:+128,:K]^T.
// BK=64 as two 32-wide panels per barrier pair. epi(m, n, val) per element.
constexpr int PANEL = 128 * 32;

template<typename Epi>
__device__ __forceinline__ void gemm_tile_e(const unsigned short* __restrict__ A,
                                            const unsigned short* __restrict__ W,
                                            int K, int m0, int n0,
                                            unsigned short* As, unsigned short* Bs,
                                            Epi&& epi) {
    const int tid  = threadIdx.x;
    const int lane = tid & 63;
    const int wave = tid >> 6;
    const int wm = (wave >> 1) * 64, wn = (wave & 1) * 64;

    const int srow = tid >> 2;
    const int scol = (tid & 3) * 8;
    const unsigned short* Ag = A + (size_t)(m0 + srow) * K + scol;
    const unsigned short* Wg = W + (size_t)(n0 + srow) * K + scol;
    unsigned short* Asl = As + tid * 8;
    unsigned short* Bsl = Bs + tid * 8;

    const int fm = lane & 15;
    const int fk = (lane >> 4) * 8;

    f32x4 acc[4][4];
#pragma unroll
    for (int i = 0; i < 4; i++)
#pragma unroll
        for (int j = 0; j < 4; j++) acc[i][j] = (f32x4){0.f, 0.f, 0.f, 0.f};

    for (int k0 = 0; k0 < K; k0 += 64) {
        __syncthreads();
        load_lds16(Ag + k0, Asl);
        load_lds16(Ag + (size_t)64 * K + k0, Asl + 64 * 32);
        load_lds16(Wg + k0, Bsl);
        load_lds16(Wg + (size_t)64 * K + k0, Bsl + 64 * 32);
        load_lds16(Ag + k0 + 32, Asl + PANEL);
        load_lds16(Ag + (size_t)64 * K + k0 + 32, Asl + PANEL + 64 * 32);
        load_lds16(Wg + k0 + 32, Bsl + PANEL);
        load_lds16(Wg + (size_t)64 * K + k0 + 32, Bsl + PANEL + 64 * 32);
        __syncthreads();

#pragma unroll
        for (int hp = 0; hp < 2; hp++) {
            const unsigned short* Ap = As + hp * PANEL;
            const unsigned short* Bp = Bs + hp * PANEL;
            s16x8 af[4], bf[4];
#pragma unroll
            for (int i = 0; i < 4; i++) {
                af[i] = *(const s16x8*)&Ap[(wm + i * 16 + fm) * 32 + fk];
                bf[i] = *(const s16x8*)&Bp[(wn + i * 16 + fm) * 32 + fk];
            }
#pragma unroll
            for (int i = 0; i < 4; i++)
#pragma unroll
                for (int j = 0; j < 4; j++)
                    acc[i][j] = __builtin_amdgcn_mfma_f32_16x16x32_bf16(af[i], bf[j], acc[i][j], 0, 0, 0);
        }
    }

    const int fr = (lane >> 4) * 4;
#pragma unroll
    for (int j = 0; j < 4; j++) {
        int col = n0 + wn + j * 16 + fm;
#pragma unroll
        for (int i = 0; i < 4; i++) {
            int row = m0 + wm + i * 16 + fr;
#pragma unroll
            for (int r = 0; r < 4; r++)
                epi(row + r, col, acc[i][j][r]);
        }
    }
}

// Fused QKV emitting fragment-native packed layouts:
//   qpack: per (b,h): [dgrp 8][q 256][8]   (16384 elems)
//   kpack: per (b,h): [dgrp 8][key 512][8] (32768 elems)
//   vpack: per (b,h): [keygrp 64][d 64][8] (32768 elems)
__global__ __launch_bounds__(256) void qkv_fused(const unsigned short* __restrict__ padded,
                                                 const unsigned short* __restrict__ text,
                                                 const unsigned short* __restrict__ wqkv,
                                                 const float* __restrict__ bqkv,
                                                 unsigned short* __restrict__ qpack,
                                                 unsigned short* __restrict__ kpack,
                                                 unsigned short* __restrict__ vpack) {
    __shared__ __align__(16) unsigned short As[2 * PANEL];
    __shared__ __align__(16) unsigned short Bs[2 * PANEL];
    int flat = blockIdx.x;
    if (flat < 256) {
        // Q: M=4096 tokens, cols = h*64+d
        gemm_tile_e(padded, wqkv, D, (flat >> 3) * 128, (flat & 7) * 128, As, Bs,
            [&](int m, int col, float v) {
                float val = v + bqkv[col];
                int b = m >> 8, q = m & 255;
                int h = col >> 6, d = col & 63;
                qpack[(size_t)(b * H + h) * 16384 + (d >> 3) * 2048 + q * 8 + (d & 7)] = f2bf(val);
            });
    } else if (flat < 768) {
        int f = flat - 256;
        // K: M=8192 tokens, cols = h*64+d
        gemm_tile_e(text, wqkv + (size_t)D * D, D, (f >> 3) * 128, (f & 7) * 128, As, Bs,
            [&](int m, int col, float v) {
                float val = v + bqkv[D + col];
                int b = m >> 9, key = m & 511;
                int h = col >> 6, d = col & 63;
                kpack[(size_t)(b * H + h) * 32768 + (d >> 3) * 4096 + key * 8 + (d & 7)] = f2bf(val);
            });
    } else {
        int f = flat - 768;
        // V^T: A = wv rows (M=1024 = h*64+d), W = text (cols = tokens), bias by row m
        gemm_tile_e(wqkv + 2 * (size_t)D * D, text, D, (f >> 6) * 128, (f & 63) * 128, As, Bs,
            [&](int m, int col, float v) {
                float val = v + bqkv[2 * D + m];
                int h = m >> 6, d = m & 63;
                int b = col >> 9, key = col & 511;
                vpack[(size_t)(b * H + h) * 32768 + (key >> 3) * 512 + d * 8 + (key & 7)] = f2bf(val);
            });
    }
}

// attn_out GEMM, bf16 row-major out
__global__ __launch_bounds__(256) void gemm_bf(const unsigned short* __restrict__ A,
                                               const unsigned short* __restrict__ W,
                                               const float* __restrict__ bias,
                                               unsigned short* __restrict__ C, int Nn, int K) {
    __shared__ __align__(16) unsigned short As[2 * PANEL];
    __shared__ __align__(16) unsigned short Bs[2 * PANEL];
    gemm_tile_e(A, W, K, blockIdx.y * 128, blockIdx.x * 128, As, Bs,
        [&](int m, int col, float v) {
            C[(size_t)m * Nn + col] = f2bf(v + bias[col]);
        });
}

// ---------------------------------------------------------------------------
// MFMA attention on fragment-native layouts: zero __syncthreads, zero K/V LDS.
// All global fragment loads are coalesced (16 lanes x 16B contiguous per quad).
__global__ __launch_bounds__(256) void attn_mfma(const unsigned short* __restrict__ qpack,
                                                 const unsigned short* __restrict__ kpack,
                                                 const unsigned short* __restrict__ vpack,
                                                 unsigned short* __restrict__ ctx) {
    __shared__ __align__(16) unsigned short Ps[4 * 16 * 136];  // per-wave P chunk [16][136]

    const int tid = threadIdx.x;
    const int lane = tid & 63;
    const int wv = tid >> 6;
    const int fm = lane & 15;
    const int quad = lane >> 4;
    const int b = blockIdx.z, h = blockIdx.y;
    const int q0 = blockIdx.x * 64 + wv * 16;

    const unsigned short* qp = qpack + (size_t)(b * H + h) * 16384;
    const unsigned short* kp = kpack + (size_t)(b * H + h) * 32768;
    const unsigned short* vp = vpack + (size_t)(b * H + h) * 32768;

    // Q A-fragments: dgrp = 4*s + quad
    const s16x8 aq0 = *(const s16x8*)&qp[(quad)     * 2048 + (q0 + fm) * 8];
    const s16x8 aq1 = *(const s16x8*)&qp[(4 + quad) * 2048 + (q0 + fm) * 8];

    // ---- pass 1: scores ----
    f32x4 sc[32];
#pragma unroll
    for (int t = 0; t < 32; t++) {
        s16x8 bk0 = *(const s16x8*)&kp[(quad)     * 4096 + (t * 16 + fm) * 8];
        s16x8 bk1 = *(const s16x8*)&kp[(4 + quad) * 4096 + (t * 16 + fm) * 8];
        f32x4 a = (f32x4){0.f, 0.f, 0.f, 0.f};
        a = __builtin_amdgcn_mfma_f32_16x16x32_bf16(aq0, bk0, a, 0, 0, 0);
        a = __builtin_amdgcn_mfma_f32_16x16x32_bf16(aq1, bk1, a, 0, 0, 0);
        sc[t] = a;
    }

    // ---- softmax in registers (row q = quad*4+r lives on this quad's 16 lanes) ----
    const float scale = 0.125f;
    float mx[4], l[4], inv[4];
#pragma unroll
    for (int r = 0; r < 4; r++) {
        float m = sc[0][r];
#pragma unroll
        for (int t = 1; t < 32; t++) m = fmaxf(m, sc[t][r]);
        mx[r] = m;
    }
#pragma unroll
    for (int o = 1; o < 16; o <<= 1)
#pragma unroll
        for (int r = 0; r < 4; r++) mx[r] = fmaxf(mx[r], __shfl_xor(mx[r], o));
#pragma unroll
    for (int r = 0; r < 4; r++) l[r] = 0.f;
#pragma unroll
    for (int t = 0; t < 32; t++)
#pragma unroll
        for (int r = 0; r < 4; r++) {
            float e = __expf((sc[t][r] - mx[r]) * scale);
            sc[t][r] = e;
            l[r] += e;
        }
#pragma unroll
    for (int o = 1; o < 16; o <<= 1)
#pragma unroll
        for (int r = 0; r < 4; r++) l[r] += __shfl_xor(l[r], o);
#pragma unroll
    for (int r = 0; r < 4; r++) inv[r] = 1.f / l[r];

    // ---- pass 2: ctx = P @ V. P via wave-private LDS (no barrier needed). ----
    f32x4 co[4];
#pragma unroll
    for (int n = 0; n < 4; n++) co[n] = (f32x4){0.f, 0.f, 0.f, 0.f};
    unsigned short* Pw = Ps + wv * (16 * 136);

    for (int c = 0; c < 4; c++) {
#pragma unroll
        for (int t = 0; t < 8; t++)
#pragma unroll
            for (int r = 0; r < 4; r++)
                Pw[(quad * 4 + r) * 136 + t * 16 + fm] = f2bf(sc[c * 8 + t][r]);
        // within-wave ds_write -> ds_read ordering is lgkmcnt-enforced; Pw is wave-private
#pragma unroll
        for (int s = 0; s < 4; s++) {
            s16x8 ap = *(const s16x8*)&Pw[fm * 136 + s * 32 + quad * 8];
#pragma unroll
            for (int n = 0; n < 4; n++) {
                s16x8 bv = *(const s16x8*)&vp[(c * 16 + s * 4 + quad) * 512 + (n * 16 + fm) * 8];
                co[n] = __builtin_amdgcn_mfma_f32_16x16x32_bf16(ap, bv, co[n], 0, 0, 0);
            }
        }
    }

    // ---- store ctx row-major (C-layout), fold in 1/l ----
    const size_t obase = (size_t)(b * LMAX + q0) * D + h * DH;
#pragma unroll
    for (int n = 0; n < 4; n++)
#pragma unroll
        for (int r = 0; r < 4; r++)
            ctx[obase + (size_t)(quad * 4 + r) * D + n * 16 + fm] = f2bf(co[n][r] * inv[r]);
}

// ---------------------------------------------------------------------------
// Fused LayerNorm + segment-mean partial (bf16 input rows).
__global__ __launch_bounds__(256) void lnmean_kernel(const unsigned short* __restrict__ f1,
                                                     const float* __restrict__ g,
                                                     const float* __restrict__ bb,
                                                     const int* __restrict__ counts,
                                                     float* __restrict__ msum) {
    int b = blockIdx.x;
    int cnt = counts[b];
    int s0 = blockIdx.y * 32;
    int s1 = min(cnt, s0 + 32);
    if (s0 >= s1) return;
    int t = threadIdx.x;
    int wv = t >> 6, ln = t & 63;
    float4 gg = ((const float4*)g)[t];
    float4 bv = ((const float4*)bb)[t];
    float acc[4] = {0.f, 0.f, 0.f, 0.f};
    __shared__ float red[8];

    for (int s = s0; s < s1; s++) {
        const unsigned short* x = f1 + ((size_t)(b * LMAX + s)) * D;
        ushort4 u = ((const ushort4*)x)[t];
        float4 val = {bf2f(u.x), bf2f(u.y), bf2f(u.z), bf2f(u.w)};
        float sm = val.x + val.y + val.z + val.w;
        float ss = val.x * val.x + val.y * val.y + val.z * val.z + val.w * val.w;
#pragma unroll
        for (int o = 32; o; o >>= 1) { sm += __shfl_xor(sm, o); ss += __shfl_xor(ss, o); }
        if (ln == 0) { red[wv] = sm; red[4 + wv] = ss; }
        __syncthreads();
        sm = red[0] + red[1] + red[2] + red[3];
        ss = red[4] + red[5] + red[6] + red[7];
        __syncthreads();
        float mu = sm * (1.f / D);
        float var = ss * (1.f / D) - mu * mu;
        float r = rsqrtf(var + LN_EPS);
        acc[0] += (val.x - mu) * r * gg.x + bv.x;
        acc[1] += (val.y - mu) * r * gg.y + bv.y;
        acc[2] += (val.z - mu) * r * gg.z + bv.z;
        acc[3] += (val.w - mu) * r * gg.w + bv.w;
    }
    float inv = 1.f / (float)max(cnt, 1);
#pragma unroll
    for (int j = 0; j < 4; j++)
        atomicAdd(&msum[(size_t)b * D + t * 4 + j], acc[j] * inv);
}

// Mini projection: out[b][n] = msum[b] . proj_w[n] + bias[n]  (fp32).
__global__ __launch_bounds__(256) void tproj_kernel(const float* __restrict__ msum,
                                                    const float* __restrict__ W,
                                                    const float* __restrict__ bias,
                                                    float* __restrict__ out) {
    int lane = threadIdx.x & 63;
    int n = blockIdx.x * 4 + (threadIdx.x >> 6);
    float4 wr[4];
#pragma unroll
    for (int i = 0; i < 4; i++)
        wr[i] = *(const float4*)&W[(size_t)n * D + i * 256 + lane * 4];
    float bn = bias[n];
    for (int b = 0; b < B; b++) {
        float s = 0.f;
#pragma unroll
        for (int i = 0; i < 4; i++) {
            float4 m4 = *(const float4*)&msum[(size_t)b * D + i * 256 + lane * 4];
            s += m4.x * wr[i].x + m4.y * wr[i].y + m4.z * wr[i].z + m4.w * wr[i].w;
        }
#pragma unroll
        for (int o = 32; o; o >>= 1) s += __shfl_xor(s, o);
        if (lane == 0) out[(size_t)b * D + n] = s + bn;
    }
}

// ---------------------------------------------------------------------------
extern "C" void kernel_launch(void* const* d_in, const int* in_sizes, int n_in,
                              void* d_out, int out_size, void* d_ws, size_t ws_size,
                              hipStream_t stream) {
    const float* struct_token = (const float*)d_in[0];
    const float* text_token   = (const float*)d_in[1];
    const float* in_proj_w    = (const float*)d_in[2];
    const float* in_proj_b    = (const float*)d_in[3];
    const float* attn_out_w   = (const float*)d_in[4];
    const float* attn_out_b   = (const float*)d_in[5];
    const float* ln_g         = (const float*)d_in[6];
    const float* ln_b         = (const float*)d_in[7];
    const float* proj_w       = (const float*)d_in[8];
    const float* proj_b       = (const float*)d_in[9];
    const int*   sb           = (const int*)d_in[10];
    float* out = (float*)d_out;

    const size_t MQ  = (size_t)B * LMAX;     // 4096
    const size_t MKV = (size_t)B * LT;       // 8192

    char* p = (char*)d_ws;
    unsigned short* padded_b = (unsigned short*)p;  p += MQ * D * 2;
    unsigned short* text_b   = (unsigned short*)p;  p += MKV * D * 2;
    unsigned short* wqkv_b   = (unsigned short*)p;  p += (size_t)3 * D * D * 2;
    unsigned short* wattn_b  = (unsigned short*)p;  p += (size_t)D * D * 2;
    unsigned short* qpack    = (unsigned short*)p;  p += MQ * D * 2;
    unsigned short* kpack    = (unsigned short*)p;  p += MKV * D * 2;
    unsigned short* vpack    = (unsigned short*)p;  p += MKV * D * 2;
    unsigned short* ctx_b    = (unsigned short*)p;  p += MQ * D * 2;
    unsigned short* f1b      = (unsigned short*)p;  p += MQ * D * 2;
    float* msum = (float*)p;  p += (size_t)B * D * 4;
    int* pos    = (int*)p;  p += N * 4;
    int* counts = (int*)p;  p += B * 4;
    int* starts = (int*)p;  p += B * 4;

    hipMemsetAsync(padded_b, 0, MQ * D * 2, stream);
    hipMemsetAsync(msum, 0, (size_t)B * D * 4, stream);
    prep_kernel<<<1, 256, 0, stream>>>(sb, counts, starts, pos);
    scatter_kernel<<<N, 256, 0, stream>>>(struct_token, sb, pos, padded_b);

    cast3_kernel<<<6144, 256, 0, stream>>>(
        text_token, text_b, (int)(MKV * D),
        in_proj_w,  wqkv_b, 3 * D * D,
        attn_out_w, wattn_b, D * D);

    qkv_fused<<<1280, 256, 0, stream>>>(padded_b, text_b, wqkv_b, in_proj_b,
                                        qpack, kpack, vpack);

    attn_mfma<<<dim3(LMAX / 64, H, B), 256, 0, stream>>>(qpack, kpack, vpack, ctx_b);

    gemm_bf<<<dim3(D / 128, MQ / 128), 256, 0, stream>>>(ctx_b, wattn_b, attn_out_b, f1b, D, D);

    lnmean_kernel<<<dim3(B, LMAX / 32), 256, 0, stream>>>(f1b, ln_g, ln_b, counts, msum);

    tproj_kernel<<<256, 256, 0, stream>>>(msum, proj_w, proj_b, out);
}

// Round 7
// 286.731 us; speedup vs baseline: 1.2037x; 1.0719x over previous
//
#include <hip/hip_runtime.h>

// Problem constants
constexpr int B  = 16;
constexpr int LT = 512;
constexpr int D  = 1024;
constexpr int N  = 4096;
constexpr int H  = 16;
constexpr int DH = D / H;       // 64
constexpr int LMAX = N / B;     // 256
constexpr float LN_EPS = 1e-5f;

typedef short  s16x8 __attribute__((ext_vector_type(8)));
typedef float  f32x4 __attribute__((ext_vector_type(4)));

__device__ __forceinline__ unsigned short f2bf(float x) {
    unsigned int u = __float_as_uint(x);
    unsigned int r = (u + 0x7fffu + ((u >> 16) & 1u)) >> 16;   // RNE
    return (unsigned short)r;
}
__device__ __forceinline__ float bf2f(unsigned short u) {
    return __uint_as_float((unsigned int)u << 16);
}

__device__ __forceinline__ void load_lds16(const void* g, void* l) {
    __builtin_amdgcn_global_load_lds(
        (const __attribute__((address_space(1))) unsigned int*)g,
        (__attribute__((address_space(3))) unsigned int*)l, 16, 0, 0);
}

// ---------------------------------------------------------------------------
__global__ void prep_kernel(const int* __restrict__ sb, int* __restrict__ counts,
                            int* __restrict__ starts, int* __restrict__ pos) {
    __shared__ int s_counts[B], s_starts[B];
    int t = threadIdx.x;
    if (t < B) s_counts[t] = 0;
    __syncthreads();
    for (int i = t; i < N; i += 256) atomicAdd(&s_counts[sb[i]], 1);
    __syncthreads();
    if (t == 0) {
        int run = 0;
        for (int b = 0; b < B; b++) { s_starts[b] = run; run += s_counts[b]; }
    }
    __syncthreads();
    if (t < B) { counts[t] = s_counts[t]; starts[t] = s_starts[t]; }
    for (int i = t; i < N; i += 256) {
        int b = sb[i];
        pos[i] = i - s_starts[b];
    }
}

// ---------------------------------------------------------------------------
__global__ void scatter_kernel(const float* __restrict__ st, const int* __restrict__ sb,
                               const int* __restrict__ pos, unsigned short* __restrict__ padded) {
    int i = blockIdx.x;
    int b = sb[i], p = pos[i];
    int d = threadIdx.x * 4;
    float4 v = *(const float4*)&st[(size_t)i * D + d];
    ushort4 o;
    o.x = f2bf(v.x); o.y = f2bf(v.y); o.z = f2bf(v.z); o.w = f2bf(v.w);
    *(ushort4*)&padded[((size_t)(b * LMAX + p)) * D + d] = o;
}

// fused fp32->bf16 cast of three regions
__global__ __launch_bounds__(256) void cast3_kernel(
        const float* __restrict__ x0, unsigned short* __restrict__ y0, int n0,
        const float* __restrict__ x1, unsigned short* __restrict__ y1, int n1,
        const float* __restrict__ x2, unsigned short* __restrict__ y2, int n2) {
    long long i = (long long)(blockIdx.x * 256 + threadIdx.x) * 8;
    const float* x; unsigned short* y;
    if (i < n0)                { x = x0 + i; y = y0 + i; }
    else if (i < (long long)n0 + n1) { long long j = i - n0; x = x1 + j; y = y1 + j; }
    else if (i < (long long)n0 + n1 + n2) { long long j = i - n0 - n1; x = x2 + j; y = y2 + j; }
    else return;
    float4 a = *(const float4*)x;
    float4 b = *(const float4*)(x + 4);
    ushort4 o1, o2;
    o1.x = f2bf(a.x); o1.y = f2bf(a.y); o1.z = f2bf(a.z); o1.w = f2bf(a.w);
    o2.x = f2bf(b.x); o2.y = f2bf(b.y); o2.z = f2bf(b.z); o2.w = f2bf(b.w);
    *(ushort4*)y = o1;
    *(ushort4*)(y + 4) = o2;
}

// ---------------------------------------------------------------------------
// GEMM tile body with custom epilogue. C tile = A[m0:+128,:K] @ W[n0:+128,:K]^T.
// BK=64 as two 32-wide panels per barrier pair. epi(m, n, val) per element.
constexpr int PANEL = 128 * 32;

template<typename Epi>
__device__ __forceinline__ void gemm_tile_e(const unsigned short* __restrict__ A,
                                            const unsigned short* __restrict__ W,
                                            int K, int m0, int n0,
                                            unsigned short* As, unsigned short* Bs,
                                            Epi&& epi) {
    const int tid  = threadIdx.x;
    const int lane = tid & 63;
    const int wave = tid >> 6;
    const int wm = (wave >> 1) * 64, wn = (wave & 1) * 64;

    const int srow = tid >> 2;
    const int scol = (tid & 3) * 8;
    const unsigned short* Ag = A + (size_t)(m0 + srow) * K + scol;
    const unsigned short* Wg = W + (size_t)(n0 + srow) * K + scol;
    unsigned short* Asl = As + tid * 8;
    unsigned short* Bsl = Bs + tid * 8;

    const int fm = lane & 15;
    const int fk = (lane >> 4) * 8;

    f32x4 acc[4][4];
#pragma unroll
    for (int i = 0; i < 4; i++)
#pragma unroll
        for (int j = 0; j < 4; j++) acc[i][j] = (f32x4){0.f, 0.f, 0.f, 0.f};

    for (int k0 = 0; k0 < K; k0 += 64) {
        __syncthreads();
        load_lds16(Ag + k0, Asl);
        load_lds16(Ag + (size_t)64 * K + k0, Asl + 64 * 32);
        load_lds16(Wg + k0, Bsl);
        load_lds16(Wg + (size_t)64 * K + k0, Bsl + 64 * 32);
        load_lds16(Ag + k0 + 32, Asl + PANEL);
        load_lds16(Ag + (size_t)64 * K + k0 + 32, Asl + PANEL + 64 * 32);
        load_lds16(Wg + k0 + 32, Bsl + PANEL);
        load_lds16(Wg + (size_t)64 * K + k0 + 32, Bsl + PANEL + 64 * 32);
        __syncthreads();

#pragma unroll
        for (int hp = 0; hp < 2; hp++) {
            const unsigned short* Ap = As + hp * PANEL;
            const unsigned short* Bp = Bs + hp * PANEL;
            s16x8 af[4], bf[4];
#pragma unroll
            for (int i = 0; i < 4; i++) {
                af[i] = *(const s16x8*)&Ap[(wm + i * 16 + fm) * 32 + fk];
                bf[i] = *(const s16x8*)&Bp[(wn + i * 16 + fm) * 32 + fk];
            }
#pragma unroll
            for (int i = 0; i < 4; i++)
#pragma unroll
                for (int j = 0; j < 4; j++)
                    acc[i][j] = __builtin_amdgcn_mfma_f32_16x16x32_bf16(af[i], bf[j], acc[i][j], 0, 0, 0);
        }
    }

    const int fr = (lane >> 4) * 4;
#pragma unroll
    for (int j = 0; j < 4; j++) {
        int col = n0 + wn + j * 16 + fm;
#pragma unroll
        for (int i = 0; i < 4; i++) {
            int row = m0 + wm + i * 16 + fr;
#pragma unroll
            for (int r = 0; r < 4; r++)
                epi(row + r, col, acc[i][j][r]);
        }
    }
}

// Fused QKV emitting fragment-native packed layouts:
//   qpack: per (b,h): [dgrp 8][q 256][8]   (16384 elems)
//   kpack: per (b,h): [dgrp 8][key 512][8] (32768 elems)
//   vpack: per (b,h): [keygrp 64][d 64][8] (32768 elems)
__global__ __launch_bounds__(256) void qkv_fused(const unsigned short* __restrict__ padded,
                                                 const unsigned short* __restrict__ text,
                                                 const unsigned short* __restrict__ wqkv,
                                                 const float* __restrict__ bqkv,
                                                 unsigned short* __restrict__ qpack,
                                                 unsigned short* __restrict__ kpack,
                                                 unsigned short* __restrict__ vpack) {
    __shared__ __align__(16) unsigned short As[2 * PANEL];
    __shared__ __align__(16) unsigned short Bs[2 * PANEL];
    int flat = blockIdx.x;
    if (flat < 256) {
        // Q: M=4096 tokens, cols = h*64+d
        gemm_tile_e(padded, wqkv, D, (flat >> 3) * 128, (flat & 7) * 128, As, Bs,
            [&](int m, int col, float v) {
                float val = v + bqkv[col];
                int b = m >> 8, q = m & 255;
                int h = col >> 6, d = col & 63;
                qpack[(size_t)(b * H + h) * 16384 + (d >> 3) * 2048 + q * 8 + (d & 7)] = f2bf(val);
            });
    } else if (flat < 768) {
        int f = flat - 256;
        // K: M=8192 tokens, cols = h*64+d
        gemm_tile_e(text, wqkv + (size_t)D * D, D, (f >> 3) * 128, (f & 7) * 128, As, Bs,
            [&](int m, int col, float v) {
                float val = v + bqkv[D + col];
                int b = m >> 9, key = m & 511;
                int h = col >> 6, d = col & 63;
                kpack[(size_t)(b * H + h) * 32768 + (d >> 3) * 4096 + key * 8 + (d & 7)] = f2bf(val);
            });
    } else {
        int f = flat - 768;
        // V^T: A = wv rows (M=1024 = h*64+d), W = text (cols = tokens), bias by row m
        gemm_tile_e(wqkv + 2 * (size_t)D * D, text, D, (f >> 6) * 128, (f & 63) * 128, As, Bs,
            [&](int m, int col, float v) {
                float val = v + bqkv[2 * D + m];
                int h = m >> 6, d = m & 63;
                int b = col >> 9, key = col & 511;
                vpack[(size_t)(b * H + h) * 32768 + (key >> 3) * 512 + d * 8 + (key & 7)] = f2bf(val);
            });
    }
}

// attn_out GEMM, bf16 row-major out
__global__ __launch_bounds__(256) void gemm_bf(const unsigned short* __restrict__ A,
                                               const unsigned short* __restrict__ W,
                                               const float* __restrict__ bias,
                                               unsigned short* __restrict__ C, int Nn, int K) {
    __shared__ __align__(16) unsigned short As[2 * PANEL];
    __shared__ __align__(16) unsigned short Bs[2 * PANEL];
    gemm_tile_e(A, W, K, blockIdx.y * 128, blockIdx.x * 128, As, Bs,
        [&](int m, int col, float v) {
            C[(size_t)m * Nn + col] = f2bf(v + bias[col]);
        });
}

// ---------------------------------------------------------------------------
// MFMA attention: block = (b, h, q-half of 128 rows), 512 thr = 8 waves,
// 1 q-tile (16 rows) per wave. K and V staged as bulk 32 KB linear chunks via
// global_load_lds (packed layouts are contiguous per (b,h)); 8 barriers total.
constexpr int PKW = 72;   // P row stride (16B-aligned, bank-staggered)

__global__ __launch_bounds__(512) void attn_mfma(const unsigned short* __restrict__ qpack,
                                                 const unsigned short* __restrict__ kpack,
                                                 const unsigned short* __restrict__ vpack,
                                                 unsigned short* __restrict__ ctx) {
    __shared__ __align__(16) unsigned short KV[16384];        // 32 KB chunk (K or V)
    __shared__ __align__(16) unsigned short Ps[8 * 16 * PKW]; // 18 KB, per-wave P

    const int tid = threadIdx.x;
    const int lane = tid & 63;
    const int wv = tid >> 6;              // 0..7
    const int fm = lane & 15;
    const int quad = lane >> 4;
    const int h = blockIdx.x, b = blockIdx.y, half = blockIdx.z;
    const int q0 = half * 128 + wv * 16;

    const unsigned short* qp = qpack + (size_t)(b * H + h) * 16384;
    const unsigned short* kp = kpack + (size_t)(b * H + h) * 32768;
    const unsigned short* vp = vpack + (size_t)(b * H + h) * 32768;

    // Q A-fragments (direct, coalesced: 16 lanes x 16B contiguous per quad)
    const s16x8 aq0 = *(const s16x8*)&qp[quad * 2048 + (q0 + fm) * 8];
    const s16x8 aq1 = *(const s16x8*)&qp[(4 + quad) * 2048 + (q0 + fm) * 8];

    f32x4 sc[32];

    // ---- pass 1: scores; two K chunks of 256 keys (32 KB each) ----
    for (int kc = 0; kc < 2; kc++) {
        __syncthreads();
        // LDS chunk layout [dgrp 8][key 256][8]; dst is linear in f -> pure copy
#pragma unroll
        for (int it = 0; it < 4; it++) {
            int f = it * 512 + tid;
            load_lds16(kp + (f >> 8) * 4096 + kc * 2048 + (f & 255) * 8, KV + f * 8);
        }
        __syncthreads();
#pragma unroll
        for (int t = 0; t < 16; t++) {
            s16x8 bk0 = *(const s16x8*)&KV[quad * 2048 + (t * 16 + fm) * 8];
            s16x8 bk1 = *(const s16x8*)&KV[(4 + quad) * 2048 + (t * 16 + fm) * 8];
            f32x4 a = (f32x4){0.f, 0.f, 0.f, 0.f};
            a = __builtin_amdgcn_mfma_f32_16x16x32_bf16(aq0, bk0, a, 0, 0, 0);
            a = __builtin_amdgcn_mfma_f32_16x16x32_bf16(aq1, bk1, a, 0, 0, 0);
            sc[kc * 16 + t] = a;
        }
    }

    // ---- softmax in registers (row q = quad*4+r lives on this quad's 16 lanes) ----
    const float scale = 0.125f;
    float mx[4], l[4], inv[4];
#pragma unroll
    for (int r = 0; r < 4; r++) {
        float m = sc[0][r];
#pragma unroll
        for (int t = 1; t < 32; t++) m = fmaxf(m, sc[t][r]);
        mx[r] = m;
    }
#pragma unroll
    for (int o = 1; o < 16; o <<= 1)
#pragma unroll
        for (int r = 0; r < 4; r++) mx[r] = fmaxf(mx[r], __shfl_xor(mx[r], o));
#pragma unroll
    for (int r = 0; r < 4; r++) l[r] = 0.f;
#pragma unroll
    for (int t = 0; t < 32; t++)
#pragma unroll
        for (int r = 0; r < 4; r++) {
            float e = __expf((sc[t][r] - mx[r]) * scale);
            sc[t][r] = e;
            l[r] += e;
        }
#pragma unroll
    for (int o = 1; o < 16; o <<= 1)
#pragma unroll
        for (int r = 0; r < 4; r++) l[r] += __shfl_xor(l[r], o);
#pragma unroll
    for (int r = 0; r < 4; r++) inv[r] = 1.f / l[r];

    // ---- pass 2: ctx = P @ V; two V chunks (32 KB, fully linear) ----
    f32x4 co[4];
#pragma unroll
    for (int n = 0; n < 4; n++) co[n] = (f32x4){0.f, 0.f, 0.f, 0.f};
    unsigned short* Pw = Ps + wv * (16 * PKW);

    for (int vc = 0; vc < 2; vc++) {
        __syncthreads();
#pragma unroll
        for (int it = 0; it < 4; it++) {
            int f = it * 512 + tid;
            load_lds16(vp + vc * 16384 + f * 8, KV + f * 8);
        }
        __syncthreads();
        // V chunk layout [kg 32][d 64][8]
        for (int cs = 0; cs < 4; cs++) {
            int c = vc * 4 + cs;   // 64-key subchunk
#pragma unroll
            for (int tt = 0; tt < 4; tt++)
#pragma unroll
                for (int r = 0; r < 4; r++)
                    Pw[(quad * 4 + r) * PKW + tt * 16 + fm] = f2bf(sc[c * 4 + tt][r]);
            // wave-private Pw: ds_write->ds_read ordering via lgkmcnt, no barrier
#pragma unroll
            for (int s = 0; s < 2; s++) {
                s16x8 ap = *(const s16x8*)&Pw[fm * PKW + s * 32 + quad * 8];
#pragma unroll
                for (int n = 0; n < 4; n++) {
                    s16x8 bv = *(const s16x8*)&KV[(cs * 8 + s * 4 + quad) * 512 + (n * 16 + fm) * 8];
                    co[n] = __builtin_amdgcn_mfma_f32_16x16x32_bf16(ap, bv, co[n], 0, 0, 0);
                }
            }
        }
    }

    // ---- store ctx row-major (C-layout), fold in 1/l ----
    const size_t obase = (size_t)(b * LMAX + q0) * D + h * DH;
#pragma unroll
    for (int n = 0; n < 4; n++)
#pragma unroll
        for (int r = 0; r < 4; r++)
            ctx[obase + (size_t)(quad * 4 + r) * D + n * 16 + fm] = f2bf(co[n][r] * inv[r]);
}

// ---------------------------------------------------------------------------
// Fused LayerNorm + segment-mean partial (bf16 input rows).
__global__ __launch_bounds__(256) void lnmean_kernel(const unsigned short* __restrict__ f1,
                                                     const float* __restrict__ g,
                                                     const float* __restrict__ bb,
                                                     const int* __restrict__ counts,
                                                     float* __restrict__ msum) {
    int b = blockIdx.x;
    int cnt = counts[b];
    int s0 = blockIdx.y * 32;
    int s1 = min(cnt, s0 + 32);
    if (s0 >= s1) return;
    int t = threadIdx.x;
    int wv = t >> 6, ln = t & 63;
    float4 gg = ((const float4*)g)[t];
    float4 bv = ((const float4*)bb)[t];
    float acc[4] = {0.f, 0.f, 0.f, 0.f};
    __shared__ float red[8];

    for (int s = s0; s < s1; s++) {
        const unsigned short* x = f1 + ((size_t)(b * LMAX + s)) * D;
        ushort4 u = ((const ushort4*)x)[t];
        float4 val = {bf2f(u.x), bf2f(u.y), bf2f(u.z), bf2f(u.w)};
        float sm = val.x + val.y + val.z + val.w;
        float ss = val.x * val.x + val.y * val.y + val.z * val.z + val.w * val.w;
#pragma unroll
        for (int o = 32; o; o >>= 1) { sm += __shfl_xor(sm, o); ss += __shfl_xor(ss, o); }
        if (ln == 0) { red[wv] = sm; red[4 + wv] = ss; }
        __syncthreads();
        sm = red[0] + red[1] + red[2] + red[3];
        ss = red[4] + red[5] + red[6] + red[7];
        __syncthreads();
        float mu = sm * (1.f / D);
        float var = ss * (1.f / D) - mu * mu;
        float r = rsqrtf(var + LN_EPS);
        acc[0] += (val.x - mu) * r * gg.x + bv.x;
        acc[1] += (val.y - mu) * r * gg.y + bv.y;
        acc[2] += (val.z - mu) * r * gg.z + bv.z;
        acc[3] += (val.w - mu) * r * gg.w + bv.w;
    }
    float inv = 1.f / (float)max(cnt, 1);
#pragma unroll
    for (int j = 0; j < 4; j++)
        atomicAdd(&msum[(size_t)b * D + t * 4 + j], acc[j] * inv);
}

// Mini projection: out[b][n] = msum[b] . proj_w[n] + bias[n]  (fp32).
__global__ __launch_bounds__(256) void tproj_kernel(const float* __restrict__ msum,
                                                    const float* __restrict__ W,
                                                    const float* __restrict__ bias,
                                                    float* __restrict__ out) {
    int lane = threadIdx.x & 63;
    int n = blockIdx.x * 4 + (threadIdx.x >> 6);
    float4 wr[4];
#pragma unroll
    for (int i = 0; i < 4; i++)
        wr[i] = *(const float4*)&W[(size_t)n * D + i * 256 + lane * 4];
    float bn = bias[n];
    for (int b = 0; b < B; b++) {
        float s = 0.f;
#pragma unroll
        for (int i = 0; i < 4; i++) {
            float4 m4 = *(const float4*)&msum[(size_t)b * D + i * 256 + lane * 4];
            s += m4.x * wr[i].x + m4.y * wr[i].y + m4.z * wr[i].z + m4.w * wr[i].w;
        }
#pragma unroll
        for (int o = 32; o; o >>= 1) s += __shfl_xor(s, o);
        if (lane == 0) out[(size_t)b * D + n] = s + bn;
    }
}

// ---------------------------------------------------------------------------
extern "C" void kernel_launch(void* const* d_in, const int* in_sizes, int n_in,
                              void* d_out, int out_size, void* d_ws, size_t ws_size,
                              hipStream_t stream) {
    const float* struct_token = (const float*)d_in[0];
    const float* text_token   = (const float*)d_in[1];
    const float* in_proj_w    = (const float*)d_in[2];
    const float* in_proj_b    = (const float*)d_in[3];
    const float* attn_out_w   = (const float*)d_in[4];
    const float* attn_out_b   = (const float*)d_in[5];
    const float* ln_g         = (const float*)d_in[6];
    const float* ln_b         = (const float*)d_in[7];
    const float* proj_w       = (const float*)d_in[8];
    const float* proj_b       = (const float*)d_in[9];
    const int*   sb           = (const int*)d_in[10];
    float* out = (float*)d_out;

    const size_t MQ  = (size_t)B * LMAX;     // 4096
    const size_t MKV = (size_t)B * LT;       // 8192

    char* p = (char*)d_ws;
    unsigned short* padded_b = (unsigned short*)p;  p += MQ * D * 2;
    unsigned short* text_b   = (unsigned short*)p;  p += MKV * D * 2;
    unsigned short* wqkv_b   = (unsigned short*)p;  p += (size_t)3 * D * D * 2;
    unsigned short* wattn_b  = (unsigned short*)p;  p += (size_t)D * D * 2;
    unsigned short* qpack    = (unsigned short*)p;  p += MQ * D * 2;
    unsigned short* kpack    = (unsigned short*)p;  p += MKV * D * 2;
    unsigned short* vpack    = (unsigned short*)p;  p += MKV * D * 2;
    unsigned short* ctx_b    = (unsigned short*)p;  p += MQ * D * 2;
    unsigned short* f1b      = (unsigned short*)p;  p += MQ * D * 2;
    float* msum = (float*)p;  p += (size_t)B * D * 4;
    int* pos    = (int*)p;  p += N * 4;
    int* counts = (int*)p;  p += B * 4;
    int* starts = (int*)p;  p += B * 4;

    hipMemsetAsync(padded_b, 0, MQ * D * 2, stream);
    hipMemsetAsync(msum, 0, (size_t)B * D * 4, stream);
    prep_kernel<<<1, 256, 0, stream>>>(sb, counts, starts, pos);
    scatter_kernel<<<N, 256, 0, stream>>>(struct_token, sb, pos, padded_b);

    cast3_kernel<<<6144, 256, 0, stream>>>(
        text_token, text_b, (int)(MKV * D),
        in_proj_w,  wqkv_b, 3 * D * D,
        attn_out_w, wattn_b, D * D);

    qkv_fused<<<1280, 256, 0, stream>>>(padded_b, text_b, wqkv_b, in_proj_b,
                                        qpack, kpack, vpack);

    // grid (H, B, 2): the two q-halves of one (b,h) are 256 flat-blocks apart
    // -> same XCD under round-robin dispatch -> K/V L2 reuse.
    attn_mfma<<<dim3(H, B, 2), 512, 0, stream>>>(qpack, kpack, vpack, ctx_b);

    gemm_bf<<<dim3(D / 128, MQ / 128), 256, 0, stream>>>(ctx_b, wattn_b, attn_out_b, f1b, D, D);

    lnmean_kernel<<<dim3(B, LMAX / 32), 256, 0, stream>>>(f1b, ln_g, ln_b, counts, msum);

    tproj_kernel<<<256, 256, 0, stream>>>(msum, proj_w, proj_b, out);
}

// Round 8
// 273.653 us; speedup vs baseline: 1.2612x; 1.0478x over previous
//
#include <hip/hip_runtime.h>

// Problem constants
constexpr int B  = 16;
constexpr int LT = 512;
constexpr int D  = 1024;
constexpr int N  = 4096;
constexpr int H  = 16;
constexpr int DH = D / H;       // 64
constexpr int LMAX = N / B;     // 256
constexpr float LN_EPS = 1e-5f;

typedef short  s16x8 __attribute__((ext_vector_type(8)));
typedef float  f32x4 __attribute__((ext_vector_type(4)));

__device__ __forceinline__ unsigned short f2bf(float x) {
    unsigned int u = __float_as_uint(x);
    unsigned int r = (u + 0x7fffu + ((u >> 16) & 1u)) >> 16;   // RNE
    return (unsigned short)r;
}
__device__ __forceinline__ float bf2f(unsigned short u) {
    return __uint_as_float((unsigned int)u << 16);
}

__device__ __forceinline__ void load_lds16(const void* g, void* l) {
    __builtin_amdgcn_global_load_lds(
        (const __attribute__((address_space(1))) unsigned int*)g,
        (__attribute__((address_space(3))) unsigned int*)l, 16, 0, 0);
}

// ---------------------------------------------------------------------------
// cast3 + prep in one dispatch. Blocks [0,6144) cast three fp32 regions to
// bf16; block 6144 computes counts/starts (histogram + tiny scan).
__global__ __launch_bounds__(256) void cast3_prep(
        const float* __restrict__ x0, unsigned short* __restrict__ y0, int n0,
        const float* __restrict__ x1, unsigned short* __restrict__ y1, int n1,
        const float* __restrict__ x2, unsigned short* __restrict__ y2, int n2,
        const int* __restrict__ sb, int* __restrict__ counts, int* __restrict__ starts) {
    __shared__ int s_counts[B];
    int t = threadIdx.x;
    if (blockIdx.x == 6144) {   // prep
        if (t < B) s_counts[t] = 0;
        __syncthreads();
        for (int i = t; i < N; i += 256) atomicAdd(&s_counts[sb[i]], 1);
        __syncthreads();
        if (t == 0) {
            int run = 0;
            for (int b = 0; b < B; b++) { starts[b] = run; run += s_counts[b]; }
        }
        if (t < B) counts[t] = s_counts[t];
        return;
    }
    long long i = (long long)(blockIdx.x * 256 + t) * 8;
    const float* x; unsigned short* y;
    if (i < n0)                { x = x0 + i; y = y0 + i; }
    else if (i < (long long)n0 + n1) { long long j = i - n0; x = x1 + j; y = y1 + j; }
    else if (i < (long long)n0 + n1 + n2) { long long j = i - n0 - n1; x = x2 + j; y = y2 + j; }
    else return;
    float4 a = *(const float4*)x;
    float4 b = *(const float4*)(x + 4);
    ushort4 o1, o2;
    o1.x = f2bf(a.x); o1.y = f2bf(a.y); o1.z = f2bf(a.z); o1.w = f2bf(a.w);
    o2.x = f2bf(b.x); o2.y = f2bf(b.y); o2.z = f2bf(b.z); o2.w = f2bf(b.w);
    *(ushort4*)y = o1;
    *(ushort4*)(y + 4) = o2;
}

// ---------------------------------------------------------------------------
// scatter covering ALL (b,p) slots: real tokens (contiguous segment per batch,
// src row = starts[b]+p) get cast to bf16; empty slots get zeros. Replaces
// memset(padded) + pos[]-based scatter.
__global__ void scatter_full(const float* __restrict__ st,
                             const int* __restrict__ counts,
                             const int* __restrict__ starts,
                             unsigned short* __restrict__ padded) {
    int p = blockIdx.x, b = blockIdx.y;
    int d = threadIdx.x * 4;
    size_t off = ((size_t)(b * LMAX + p)) * D + d;
    ushort4 o = {0, 0, 0, 0};
    if (p < counts[b]) {
        float4 v = *(const float4*)&st[(size_t)(starts[b] + p) * D + d];
        o.x = f2bf(v.x); o.y = f2bf(v.y); o.z = f2bf(v.z); o.w = f2bf(v.w);
    }
    *(ushort4*)&padded[off] = o;
}

// ---------------------------------------------------------------------------
// GEMM tile body with custom epilogue. C tile = A[m0:+128,:K] @ W[n0:+128,:K]^T.
// BK=64 as two 32-wide panels per barrier pair. epi(m, n, val) per element.
constexpr int PANEL = 128 * 32;

template<typename Epi>
__device__ __forceinline__ void gemm_tile_e(const unsigned short* __restrict__ A,
                                            const unsigned short* __restrict__ W,
                                            int K, int m0, int n0,
                                            unsigned short* As, unsigned short* Bs,
                                            Epi&& epi) {
    const int tid  = threadIdx.x;
    const int lane = tid & 63;
    const int wave = tid >> 6;
    const int wm = (wave >> 1) * 64, wn = (wave & 1) * 64;

    const int srow = tid >> 2;
    const int scol = (tid & 3) * 8;
    const unsigned short* Ag = A + (size_t)(m0 + srow) * K + scol;
    const unsigned short* Wg = W + (size_t)(n0 + srow) * K + scol;
    unsigned short* Asl = As + tid * 8;
    unsigned short* Bsl = Bs + tid * 8;

    const int fm = lane & 15;
    const int fk = (lane >> 4) * 8;

    f32x4 acc[4][4];
#pragma unroll
    for (int i = 0; i < 4; i++)
#pragma unroll
        for (int j = 0; j < 4; j++) acc[i][j] = (f32x4){0.f, 0.f, 0.f, 0.f};

    for (int k0 = 0; k0 < K; k0 += 64) {
        __syncthreads();
        load_lds16(Ag + k0, Asl);
        load_lds16(Ag + (size_t)64 * K + k0, Asl + 64 * 32);
        load_lds16(Wg + k0, Bsl);
        load_lds16(Wg + (size_t)64 * K + k0, Bsl + 64 * 32);
        load_lds16(Ag + k0 + 32, Asl + PANEL);
        load_lds16(Ag + (size_t)64 * K + k0 + 32, Asl + PANEL + 64 * 32);
        load_lds16(Wg + k0 + 32, Bsl + PANEL);
        load_lds16(Wg + (size_t)64 * K + k0 + 32, Bsl + PANEL + 64 * 32);
        __syncthreads();

#pragma unroll
        for (int hp = 0; hp < 2; hp++) {
            const unsigned short* Ap = As + hp * PANEL;
            const unsigned short* Bp = Bs + hp * PANEL;
            s16x8 af[4], bf[4];
#pragma unroll
            for (int i = 0; i < 4; i++) {
                af[i] = *(const s16x8*)&Ap[(wm + i * 16 + fm) * 32 + fk];
                bf[i] = *(const s16x8*)&Bp[(wn + i * 16 + fm) * 32 + fk];
            }
#pragma unroll
            for (int i = 0; i < 4; i++)
#pragma unroll
                for (int j = 0; j < 4; j++)
                    acc[i][j] = __builtin_amdgcn_mfma_f32_16x16x32_bf16(af[i], bf[j], acc[i][j], 0, 0, 0);
        }
    }

    const int fr = (lane >> 4) * 4;
#pragma unroll
    for (int j = 0; j < 4; j++) {
        int col = n0 + wn + j * 16 + fm;
#pragma unroll
        for (int i = 0; i < 4; i++) {
            int row = m0 + wm + i * 16 + fr;
#pragma unroll
            for (int r = 0; r < 4; r++)
                epi(row + r, col, acc[i][j][r]);
        }
    }
}

// Fused QKV emitting fragment-native packed layouts:
//   qpack: per (b,h): [dgrp 8][q 256][8]   (16384 elems)
//   kpack: per (b,h): [dgrp 8][key 512][8] (32768 elems)
//   vpack: per (b,h): [keygrp 64][d 64][8] (32768 elems)
__global__ __launch_bounds__(256) void qkv_fused(const unsigned short* __restrict__ padded,
                                                 const unsigned short* __restrict__ text,
                                                 const unsigned short* __restrict__ wqkv,
                                                 const float* __restrict__ bqkv,
                                                 unsigned short* __restrict__ qpack,
                                                 unsigned short* __restrict__ kpack,
                                                 unsigned short* __restrict__ vpack) {
    __shared__ __align__(16) unsigned short As[2 * PANEL];
    __shared__ __align__(16) unsigned short Bs[2 * PANEL];
    int flat = blockIdx.x;
    if (flat < 256) {
        gemm_tile_e(padded, wqkv, D, (flat >> 3) * 128, (flat & 7) * 128, As, Bs,
            [&](int m, int col, float v) {
                float val = v + bqkv[col];
                int b = m >> 8, q = m & 255;
                int h = col >> 6, d = col & 63;
                qpack[(size_t)(b * H + h) * 16384 + (d >> 3) * 2048 + q * 8 + (d & 7)] = f2bf(val);
            });
    } else if (flat < 768) {
        int f = flat - 256;
        gemm_tile_e(text, wqkv + (size_t)D * D, D, (f >> 3) * 128, (f & 7) * 128, As, Bs,
            [&](int m, int col, float v) {
                float val = v + bqkv[D + col];
                int b = m >> 9, key = m & 511;
                int h = col >> 6, d = col & 63;
                kpack[(size_t)(b * H + h) * 32768 + (d >> 3) * 4096 + key * 8 + (d & 7)] = f2bf(val);
            });
    } else {
        int f = flat - 768;
        gemm_tile_e(wqkv + 2 * (size_t)D * D, text, D, (f >> 6) * 128, (f & 63) * 128, As, Bs,
            [&](int m, int col, float v) {
                float val = v + bqkv[2 * D + m];
                int h = m >> 6, d = m & 63;
                int b = col >> 9, key = col & 511;
                vpack[(size_t)(b * H + h) * 32768 + (key >> 3) * 512 + d * 8 + (key & 7)] = f2bf(val);
            });
    }
}

// attn_out GEMM, bf16 row-major out
__global__ __launch_bounds__(256) void gemm_bf(const unsigned short* __restrict__ A,
                                               const unsigned short* __restrict__ W,
                                               const float* __restrict__ bias,
                                               unsigned short* __restrict__ C, int Nn, int K) {
    __shared__ __align__(16) unsigned short As[2 * PANEL];
    __shared__ __align__(16) unsigned short Bs[2 * PANEL];
    gemm_tile_e(A, W, K, blockIdx.y * 128, blockIdx.x * 128, As, Bs,
        [&](int m, int col, float v) {
            C[(size_t)m * Nn + col] = f2bf(v + bias[col]);
        });
}

// ---------------------------------------------------------------------------
// MFMA attention: block = (b, h, q-half of 128 rows), 512 thr = 8 waves,
// 1 q-tile (16 rows) per wave. K and V staged as bulk 32 KB linear chunks via
// global_load_lds; 8 barriers total. (Unchanged from round 7.)
constexpr int PKW = 72;

__global__ __launch_bounds__(512) void attn_mfma(const unsigned short* __restrict__ qpack,
                                                 const unsigned short* __restrict__ kpack,
                                                 const unsigned short* __restrict__ vpack,
                                                 unsigned short* __restrict__ ctx) {
    __shared__ __align__(16) unsigned short KV[16384];
    __shared__ __align__(16) unsigned short Ps[8 * 16 * PKW];

    const int tid = threadIdx.x;
    const int lane = tid & 63;
    const int wv = tid >> 6;
    const int fm = lane & 15;
    const int quad = lane >> 4;
    const int h = blockIdx.x, b = blockIdx.y, half = blockIdx.z;
    const int q0 = half * 128 + wv * 16;

    const unsigned short* qp = qpack + (size_t)(b * H + h) * 16384;
    const unsigned short* kp = kpack + (size_t)(b * H + h) * 32768;
    const unsigned short* vp = vpack + (size_t)(b * H + h) * 32768;

    const s16x8 aq0 = *(const s16x8*)&qp[quad * 2048 + (q0 + fm) * 8];
    const s16x8 aq1 = *(const s16x8*)&qp[(4 + quad) * 2048 + (q0 + fm) * 8];

    f32x4 sc[32];

    for (int kc = 0; kc < 2; kc++) {
        __syncthreads();
#pragma unroll
        for (int it = 0; it < 4; it++) {
            int f = it * 512 + tid;
            load_lds16(kp + (f >> 8) * 4096 + kc * 2048 + (f & 255) * 8, KV + f * 8);
        }
        __syncthreads();
#pragma unroll
        for (int t = 0; t < 16; t++) {
            s16x8 bk0 = *(const s16x8*)&KV[quad * 2048 + (t * 16 + fm) * 8];
            s16x8 bk1 = *(const s16x8*)&KV[(4 + quad) * 2048 + (t * 16 + fm) * 8];
            f32x4 a = (f32x4){0.f, 0.f, 0.f, 0.f};
            a = __builtin_amdgcn_mfma_f32_16x16x32_bf16(aq0, bk0, a, 0, 0, 0);
            a = __builtin_amdgcn_mfma_f32_16x16x32_bf16(aq1, bk1, a, 0, 0, 0);
            sc[kc * 16 + t] = a;
        }
    }

    const float scale = 0.125f;
    float mx[4], l[4], inv[4];
#pragma unroll
    for (int r = 0; r < 4; r++) {
        float m = sc[0][r];
#pragma unroll
        for (int t = 1; t < 32; t++) m = fmaxf(m, sc[t][r]);
        mx[r] = m;
    }
#pragma unroll
    for (int o = 1; o < 16; o <<= 1)
#pragma unroll
        for (int r = 0; r < 4; r++) mx[r] = fmaxf(mx[r], __shfl_xor(mx[r], o));
#pragma unroll
    for (int r = 0; r < 4; r++) l[r] = 0.f;
#pragma unroll
    for (int t = 0; t < 32; t++)
#pragma unroll
        for (int r = 0; r < 4; r++) {
            float e = __expf((sc[t][r] - mx[r]) * scale);
            sc[t][r] = e;
            l[r] += e;
        }
#pragma unroll
    for (int o = 1; o < 16; o <<= 1)
#pragma unroll
        for (int r = 0; r < 4; r++) l[r] += __shfl_xor(l[r], o);
#pragma unroll
    for (int r = 0; r < 4; r++) inv[r] = 1.f / l[r];

    f32x4 co[4];
#pragma unroll
    for (int n = 0; n < 4; n++) co[n] = (f32x4){0.f, 0.f, 0.f, 0.f};
    unsigned short* Pw = Ps + wv * (16 * PKW);

    for (int vc = 0; vc < 2; vc++) {
        __syncthreads();
#pragma unroll
        for (int it = 0; it < 4; it++) {
            int f = it * 512 + tid;
            load_lds16(vp + vc * 16384 + f * 8, KV + f * 8);
        }
        __syncthreads();
        for (int cs = 0; cs < 4; cs++) {
            int c = vc * 4 + cs;
#pragma unroll
            for (int tt = 0; tt < 4; tt++)
#pragma unroll
                for (int r = 0; r < 4; r++)
                    Pw[(quad * 4 + r) * PKW + tt * 16 + fm] = f2bf(sc[c * 4 + tt][r]);
#pragma unroll
            for (int s = 0; s < 2; s++) {
                s16x8 ap = *(const s16x8*)&Pw[fm * PKW + s * 32 + quad * 8];
#pragma unroll
                for (int n = 0; n < 4; n++) {
                    s16x8 bv = *(const s16x8*)&KV[(cs * 8 + s * 4 + quad) * 512 + (n * 16 + fm) * 8];
                    co[n] = __builtin_amdgcn_mfma_f32_16x16x32_bf16(ap, bv, co[n], 0, 0, 0);
                }
            }
        }
    }

    const size_t obase = (size_t)(b * LMAX + q0) * D + h * DH;
#pragma unroll
    for (int n = 0; n < 4; n++)
#pragma unroll
        for (int r = 0; r < 4; r++)
            ctx[obase + (size_t)(quad * 4 + r) * D + n * 16 + fm] = f2bf(co[n][r] * inv[r]);
}

// ---------------------------------------------------------------------------
// Barrier-free fused LN + segment-mean: grid (B, 8), 4 waves/block, 8 rows per
// wave, whole row per wave (16 cols/lane), 64-lane shfl reduction only.
__global__ __launch_bounds__(256) void lnmean_kernel(const unsigned short* __restrict__ f1,
                                                     const float* __restrict__ g,
                                                     const float* __restrict__ bb,
                                                     const int* __restrict__ counts,
                                                     float* __restrict__ msum) {
    int b = blockIdx.x;
    int t = threadIdx.x;
    int wv = t >> 6, lane = t & 63;
    int cnt = counts[b];
    int s0 = blockIdx.y * 32 + wv * 8;
    int s1 = min(cnt, s0 + 8);

    float4 gg[4], bv[4];
#pragma unroll
    for (int c = 0; c < 4; c++) {
        gg[c] = *(const float4*)&g[c * 256 + lane * 4];
        bv[c] = *(const float4*)&bb[c * 256 + lane * 4];
    }
    float4 acc[4];
#pragma unroll
    for (int c = 0; c < 4; c++) acc[c] = (float4){0.f, 0.f, 0.f, 0.f};

    for (int s = s0; s < s1; s++) {
        const unsigned short* x = f1 + ((size_t)(b * LMAX + s)) * D;
        float4 v[4];
        float sm = 0.f, ss = 0.f;
#pragma unroll
        for (int c = 0; c < 4; c++) {
            ushort4 u = *(const ushort4*)&x[c * 256 + lane * 4];
            v[c].x = bf2f(u.x); v[c].y = bf2f(u.y); v[c].z = bf2f(u.z); v[c].w = bf2f(u.w);
            sm += v[c].x + v[c].y + v[c].z + v[c].w;
            ss += v[c].x * v[c].x + v[c].y * v[c].y + v[c].z * v[c].z + v[c].w * v[c].w;
        }
#pragma unroll
        for (int o = 32; o; o >>= 1) { sm += __shfl_xor(sm, o); ss += __shfl_xor(ss, o); }
        float mu = sm * (1.f / D);
        float var = ss * (1.f / D) - mu * mu;
        float r = rsqrtf(var + LN_EPS);
#pragma unroll
        for (int c = 0; c < 4; c++) {
            acc[c].x += (v[c].x - mu) * r * gg[c].x + bv[c].x;
            acc[c].y += (v[c].y - mu) * r * gg[c].y + bv[c].y;
            acc[c].z += (v[c].z - mu) * r * gg[c].z + bv[c].z;
            acc[c].w += (v[c].w - mu) * r * gg[c].w + bv[c].w;
        }
    }
    float inv = 1.f / (float)max(cnt, 1);
#pragma unroll
    for (int c = 0; c < 4; c++) {
        int base = b * D + c * 256 + lane * 4;
        atomicAdd(&msum[base + 0], acc[c].x * inv);
        atomicAdd(&msum[base + 1], acc[c].y * inv);
        atomicAdd(&msum[base + 2], acc[c].z * inv);
        atomicAdd(&msum[base + 3], acc[c].w * inv);
    }
}

// Mini projection: out[b][n] = msum[b] . proj_w[n] + bias[n]  (fp32).
__global__ __launch_bounds__(256) void tproj_kernel(const float* __restrict__ msum,
                                                    const float* __restrict__ W,
                                                    const float* __restrict__ bias,
                                                    float* __restrict__ out) {
    int lane = threadIdx.x & 63;
    int n = blockIdx.x * 4 + (threadIdx.x >> 6);
    float4 wr[4];
#pragma unroll
    for (int i = 0; i < 4; i++)
        wr[i] = *(const float4*)&W[(size_t)n * D + i * 256 + lane * 4];
    float bn = bias[n];
    for (int b = 0; b < B; b++) {
        float s = 0.f;
#pragma unroll
        for (int i = 0; i < 4; i++) {
            float4 m4 = *(const float4*)&msum[(size_t)b * D + i * 256 + lane * 4];
            s += m4.x * wr[i].x + m4.y * wr[i].y + m4.z * wr[i].z + m4.w * wr[i].w;
        }
#pragma unroll
        for (int o = 32; o; o >>= 1) s += __shfl_xor(s, o);
        if (lane == 0) out[(size_t)b * D + n] = s + bn;
    }
}

// ---------------------------------------------------------------------------
extern "C" void kernel_launch(void* const* d_in, const int* in_sizes, int n_in,
                              void* d_out, int out_size, void* d_ws, size_t ws_size,
                              hipStream_t stream) {
    const float* struct_token = (const float*)d_in[0];
    const float* text_token   = (const float*)d_in[1];
    const float* in_proj_w    = (const float*)d_in[2];
    const float* in_proj_b    = (const float*)d_in[3];
    const float* attn_out_w   = (const float*)d_in[4];
    const float* attn_out_b   = (const float*)d_in[5];
    const float* ln_g         = (const float*)d_in[6];
    const float* ln_b         = (const float*)d_in[7];
    const float* proj_w       = (const float*)d_in[8];
    const float* proj_b       = (const float*)d_in[9];
    const int*   sb           = (const int*)d_in[10];
    float* out = (float*)d_out;

    const size_t MQ  = (size_t)B * LMAX;     // 4096
    const size_t MKV = (size_t)B * LT;       // 8192

    char* p = (char*)d_ws;
    unsigned short* padded_b = (unsigned short*)p;  p += MQ * D * 2;
    unsigned short* text_b   = (unsigned short*)p;  p += MKV * D * 2;
    unsigned short* wqkv_b   = (unsigned short*)p;  p += (size_t)3 * D * D * 2;
    unsigned short* wattn_b  = (unsigned short*)p;  p += (size_t)D * D * 2;
    unsigned short* qpack    = (unsigned short*)p;  p += MQ * D * 2;
    unsigned short* kpack    = (unsigned short*)p;  p += MKV * D * 2;
    unsigned short* vpack    = (unsigned short*)p;  p += MKV * D * 2;
    unsigned short* ctx_b    = (unsigned short*)p;  p += MQ * D * 2;
    unsigned short* f1b      = (unsigned short*)p;  p += MQ * D * 2;
    float* msum = (float*)p;  p += (size_t)B * D * 4;
    int* counts = (int*)p;  p += B * 4;
    int* starts = (int*)p;  p += B * 4;

    hipMemsetAsync(msum, 0, (size_t)B * D * 4, stream);

    // casts (blocks 0..6143) + prep (block 6144) in one dispatch
    cast3_prep<<<6145, 256, 0, stream>>>(
        text_token, text_b, (int)(MKV * D),
        in_proj_w,  wqkv_b, 3 * D * D,
        attn_out_w, wattn_b, D * D,
        sb, counts, starts);

    // scatter + zero-fill all padded slots (replaces memset + pos-based scatter)
    scatter_full<<<dim3(LMAX, B), 256, 0, stream>>>(struct_token, counts, starts, padded_b);

    qkv_fused<<<1280, 256, 0, stream>>>(padded_b, text_b, wqkv_b, in_proj_b,
                                        qpack, kpack, vpack);

    attn_mfma<<<dim3(H, B, 2), 512, 0, stream>>>(qpack, kpack, vpack, ctx_b);

    gemm_bf<<<dim3(D / 128, MQ / 128), 256, 0, stream>>>(ctx_b, wattn_b, attn_out_b, f1b, D, D);

    lnmean_kernel<<<dim3(B, 8), 256, 0, stream>>>(f1b, ln_g, ln_b, counts, msum);

    tproj_kernel<<<256, 256, 0, stream>>>(msum, proj_w, proj_b, out);
}

// Round 9
// 258.615 us; speedup vs baseline: 1.3345x; 1.0581x over previous
//
#include <hip/hip_runtime.h>

// Problem constants
constexpr int B  = 16;
constexpr int LT = 512;
constexpr int D  = 1024;
constexpr int N  = 4096;
constexpr int H  = 16;
constexpr int DH = D / H;       // 64
constexpr int LMAX = N / B;     // 256
constexpr float LN_EPS = 1e-5f;

typedef short  s16x8 __attribute__((ext_vector_type(8)));
typedef float  f32x4 __attribute__((ext_vector_type(4)));

__device__ __forceinline__ unsigned short f2bf(float x) {
    unsigned int u = __float_as_uint(x);
    unsigned int r = (u + 0x7fffu + ((u >> 16) & 1u)) >> 16;   // RNE
    return (unsigned short)r;
}
__device__ __forceinline__ float bf2f(unsigned short u) {
    return __uint_as_float((unsigned int)u << 16);
}

__device__ __forceinline__ void load_lds16(const void* g, void* l) {
    __builtin_amdgcn_global_load_lds(
        (const __attribute__((address_space(1))) unsigned int*)g,
        (__attribute__((address_space(3))) unsigned int*)l, 16, 0, 0);
}

// ---------------------------------------------------------------------------
// cast3 + prep in one dispatch.
__global__ __launch_bounds__(256) void cast3_prep(
        const float* __restrict__ x0, unsigned short* __restrict__ y0, int n0,
        const float* __restrict__ x1, unsigned short* __restrict__ y1, int n1,
        const float* __restrict__ x2, unsigned short* __restrict__ y2, int n2,
        const int* __restrict__ sb, int* __restrict__ counts, int* __restrict__ starts) {
    __shared__ int s_counts[B];
    int t = threadIdx.x;
    if (blockIdx.x == 6144) {   // prep
        if (t < B) s_counts[t] = 0;
        __syncthreads();
        for (int i = t; i < N; i += 256) atomicAdd(&s_counts[sb[i]], 1);
        __syncthreads();
        if (t == 0) {
            int run = 0;
            for (int b = 0; b < B; b++) { starts[b] = run; run += s_counts[b]; }
        }
        if (t < B) counts[t] = s_counts[t];
        return;
    }
    long long i = (long long)(blockIdx.x * 256 + t) * 8;
    const float* x; unsigned short* y;
    if (i < n0)                { x = x0 + i; y = y0 + i; }
    else if (i < (long long)n0 + n1) { long long j = i - n0; x = x1 + j; y = y1 + j; }
    else if (i < (long long)n0 + n1 + n2) { long long j = i - n0 - n1; x = x2 + j; y = y2 + j; }
    else return;
    float4 a = *(const float4*)x;
    float4 b = *(const float4*)(x + 4);
    ushort4 o1, o2;
    o1.x = f2bf(a.x); o1.y = f2bf(a.y); o1.z = f2bf(a.z); o1.w = f2bf(a.w);
    o2.x = f2bf(b.x); o2.y = f2bf(b.y); o2.z = f2bf(b.z); o2.w = f2bf(b.w);
    *(ushort4*)y = o1;
    *(ushort4*)(y + 4) = o2;
}

// ---------------------------------------------------------------------------
// scatter covering ALL (b,p) slots (segment-contiguous source), zeros for pad.
__global__ void scatter_full(const float* __restrict__ st,
                             const int* __restrict__ counts,
                             const int* __restrict__ starts,
                             unsigned short* __restrict__ padded) {
    int p = blockIdx.x, b = blockIdx.y;
    int d = threadIdx.x * 4;
    size_t off = ((size_t)(b * LMAX + p)) * D + d;
    ushort4 o = {0, 0, 0, 0};
    if (p < counts[b]) {
        float4 v = *(const float4*)&st[(size_t)(starts[b] + p) * D + d];
        o.x = f2bf(v.x); o.y = f2bf(v.y); o.z = f2bf(v.z); o.w = f2bf(v.w);
    }
    *(ushort4*)&padded[off] = o;
}

// ---------------------------------------------------------------------------
// GEMM tile body, K range [kbeg,kend), row stride K. BK=64 (two 32-panels per
// barrier pair). epi(m, n, val) per element.
constexpr int PANEL = 128 * 32;

template<typename Epi>
__device__ __forceinline__ void gemm_tile_e(const unsigned short* __restrict__ A,
                                            const unsigned short* __restrict__ W,
                                            int K, int kbeg, int kend, int m0, int n0,
                                            unsigned short* As, unsigned short* Bs,
                                            Epi&& epi) {
    const int tid  = threadIdx.x;
    const int lane = tid & 63;
    const int wave = tid >> 6;
    const int wm = (wave >> 1) * 64, wn = (wave & 1) * 64;

    const int srow = tid >> 2;
    const int scol = (tid & 3) * 8;
    const unsigned short* Ag = A + (size_t)(m0 + srow) * K + scol;
    const unsigned short* Wg = W + (size_t)(n0 + srow) * K + scol;
    unsigned short* Asl = As + tid * 8;
    unsigned short* Bsl = Bs + tid * 8;

    const int fm = lane & 15;
    const int fk = (lane >> 4) * 8;

    f32x4 acc[4][4];
#pragma unroll
    for (int i = 0; i < 4; i++)
#pragma unroll
        for (int j = 0; j < 4; j++) acc[i][j] = (f32x4){0.f, 0.f, 0.f, 0.f};

    for (int k0 = kbeg; k0 < kend; k0 += 64) {
        __syncthreads();
        load_lds16(Ag + k0, Asl);
        load_lds16(Ag + (size_t)64 * K + k0, Asl + 64 * 32);
        load_lds16(Wg + k0, Bsl);
        load_lds16(Wg + (size_t)64 * K + k0, Bsl + 64 * 32);
        load_lds16(Ag + k0 + 32, Asl + PANEL);
        load_lds16(Ag + (size_t)64 * K + k0 + 32, Asl + PANEL + 64 * 32);
        load_lds16(Wg + k0 + 32, Bsl + PANEL);
        load_lds16(Wg + (size_t)64 * K + k0 + 32, Bsl + PANEL + 64 * 32);
        __syncthreads();

#pragma unroll
        for (int hp = 0; hp < 2; hp++) {
            const unsigned short* Ap = As + hp * PANEL;
            const unsigned short* Bp = Bs + hp * PANEL;
            s16x8 af[4], bf[4];
#pragma unroll
            for (int i = 0; i < 4; i++) {
                af[i] = *(const s16x8*)&Ap[(wm + i * 16 + fm) * 32 + fk];
                bf[i] = *(const s16x8*)&Bp[(wn + i * 16 + fm) * 32 + fk];
            }
#pragma unroll
            for (int i = 0; i < 4; i++)
#pragma unroll
                for (int j = 0; j < 4; j++)
                    acc[i][j] = __builtin_amdgcn_mfma_f32_16x16x32_bf16(af[i], bf[j], acc[i][j], 0, 0, 0);
        }
    }

    const int fr = (lane >> 4) * 4;
#pragma unroll
    for (int j = 0; j < 4; j++) {
        int col = n0 + wn + j * 16 + fm;
#pragma unroll
        for (int i = 0; i < 4; i++) {
            int row = m0 + wm + i * 16 + fr;
#pragma unroll
            for (int r = 0; r < 4; r++)
                epi(row + r, col, acc[i][j][r]);
        }
    }
}

// Fused QKV with XCD-aware block swizzle: blocks sharing an A-tile get flat
// ids congruent mod 8 -> same XCD -> A re-reads hit that XCD's L2.
//   Q (256): id = n*32 + m  (m 0..31, n 0..7)   -> id%8 = m%8
//   K (512): id = n*64 + m  (m 0..63, n 0..7)   -> id%8 = m%8
//   V (512): id = m*64 + n  (m 0..7,  n 0..63)  -> id%8 = n%8 (shares text tile)
__global__ __launch_bounds__(256) void qkv_fused(const unsigned short* __restrict__ padded,
                                                 const unsigned short* __restrict__ text,
                                                 const unsigned short* __restrict__ wqkv,
                                                 const float* __restrict__ bqkv,
                                                 unsigned short* __restrict__ qpack,
                                                 unsigned short* __restrict__ kpack,
                                                 unsigned short* __restrict__ vpack) {
    __shared__ __align__(16) unsigned short As[2 * PANEL];
    __shared__ __align__(16) unsigned short Bs[2 * PANEL];
    int flat = blockIdx.x;
    if (flat < 256) {
        int m = flat & 31, n = flat >> 5;
        gemm_tile_e(padded, wqkv, D, 0, D, m * 128, n * 128, As, Bs,
            [&](int mm, int col, float v) {
                float val = v + bqkv[col];
                int b = mm >> 8, q = mm & 255;
                int h = col >> 6, d = col & 63;
                qpack[(size_t)(b * H + h) * 16384 + (d >> 3) * 2048 + q * 8 + (d & 7)] = f2bf(val);
            });
    } else if (flat < 768) {
        int f = flat - 256;
        int m = f & 63, n = f >> 6;
        gemm_tile_e(text, wqkv + (size_t)D * D, D, 0, D, m * 128, n * 128, As, Bs,
            [&](int mm, int col, float v) {
                float val = v + bqkv[D + col];
                int b = mm >> 9, key = mm & 511;
                int h = col >> 6, d = col & 63;
                kpack[(size_t)(b * H + h) * 32768 + (d >> 3) * 4096 + key * 8 + (d & 7)] = f2bf(val);
            });
    } else {
        int f = flat - 768;
        int m = f >> 6, n = f & 63;
        gemm_tile_e(wqkv + 2 * (size_t)D * D, text, D, 0, D, m * 128, n * 128, As, Bs,
            [&](int mm, int col, float v) {
                float val = v + bqkv[2 * D + mm];
                int h = mm >> 6, d = mm & 63;
                int b = col >> 9, key = col & 511;
                vpack[(size_t)(b * H + h) * 32768 + (key >> 3) * 512 + d * 8 + (key & 7)] = f2bf(val);
            });
    }
}

// attn_out GEMM, split-K=2, bf16 partial outputs (no bias; added in lnmean).
// id = kh*256 + n*32 + m -> same (m,kh) across n share A-tile on one XCD.
__global__ __launch_bounds__(256) void gemm_bf2(const unsigned short* __restrict__ A,
                                                const unsigned short* __restrict__ W,
                                                unsigned short* __restrict__ C0,
                                                unsigned short* __restrict__ C1,
                                                int Nn, int K) {
    __shared__ __align__(16) unsigned short As[2 * PANEL];
    __shared__ __align__(16) unsigned short Bs[2 * PANEL];
    int id = blockIdx.x;
    int kh = id >> 8;
    int n  = (id & 255) >> 5;
    int m  = id & 31;
    unsigned short* C = kh ? C1 : C0;
    gemm_tile_e(A, W, K, kh * 512, (kh + 1) * 512, m * 128, n * 128, As, Bs,
        [&](int mm, int col, float v) {
            C[(size_t)mm * Nn + col] = f2bf(v);
        });
}

// ---------------------------------------------------------------------------
// MFMA attention (unchanged from round 7/8).
constexpr int PKW = 72;

__global__ __launch_bounds__(512) void attn_mfma(const unsigned short* __restrict__ qpack,
                                                 const unsigned short* __restrict__ kpack,
                                                 const unsigned short* __restrict__ vpack,
                                                 unsigned short* __restrict__ ctx) {
    __shared__ __align__(16) unsigned short KV[16384];
    __shared__ __align__(16) unsigned short Ps[8 * 16 * PKW];

    const int tid = threadIdx.x;
    const int lane = tid & 63;
    const int wv = tid >> 6;
    const int fm = lane & 15;
    const int quad = lane >> 4;
    const int h = blockIdx.x, b = blockIdx.y, half = blockIdx.z;
    const int q0 = half * 128 + wv * 16;

    const unsigned short* qp = qpack + (size_t)(b * H + h) * 16384;
    const unsigned short* kp = kpack + (size_t)(b * H + h) * 32768;
    const unsigned short* vp = vpack + (size_t)(b * H + h) * 32768;

    const s16x8 aq0 = *(const s16x8*)&qp[quad * 2048 + (q0 + fm) * 8];
    const s16x8 aq1 = *(const s16x8*)&qp[(4 + quad) * 2048 + (q0 + fm) * 8];

    f32x4 sc[32];

    for (int kc = 0; kc < 2; kc++) {
        __syncthreads();
#pragma unroll
        for (int it = 0; it < 4; it++) {
            int f = it * 512 + tid;
            load_lds16(kp + (f >> 8) * 4096 + kc * 2048 + (f & 255) * 8, KV + f * 8);
        }
        __syncthreads();
#pragma unroll
        for (int t = 0; t < 16; t++) {
            s16x8 bk0 = *(const s16x8*)&KV[quad * 2048 + (t * 16 + fm) * 8];
            s16x8 bk1 = *(const s16x8*)&KV[(4 + quad) * 2048 + (t * 16 + fm) * 8];
            f32x4 a = (f32x4){0.f, 0.f, 0.f, 0.f};
            a = __builtin_amdgcn_mfma_f32_16x16x32_bf16(aq0, bk0, a, 0, 0, 0);
            a = __builtin_amdgcn_mfma_f32_16x16x32_bf16(aq1, bk1, a, 0, 0, 0);
            sc[kc * 16 + t] = a;
        }
    }

    const float scale = 0.125f;
    float mx[4], l[4], inv[4];
#pragma unroll
    for (int r = 0; r < 4; r++) {
        float m = sc[0][r];
#pragma unroll
        for (int t = 1; t < 32; t++) m = fmaxf(m, sc[t][r]);
        mx[r] = m;
    }
#pragma unroll
    for (int o = 1; o < 16; o <<= 1)
#pragma unroll
        for (int r = 0; r < 4; r++) mx[r] = fmaxf(mx[r], __shfl_xor(mx[r], o));
#pragma unroll
    for (int r = 0; r < 4; r++) l[r] = 0.f;
#pragma unroll
    for (int t = 0; t < 32; t++)
#pragma unroll
        for (int r = 0; r < 4; r++) {
            float e = __expf((sc[t][r] - mx[r]) * scale);
            sc[t][r] = e;
            l[r] += e;
        }
#pragma unroll
    for (int o = 1; o < 16; o <<= 1)
#pragma unroll
        for (int r = 0; r < 4; r++) l[r] += __shfl_xor(l[r], o);
#pragma unroll
    for (int r = 0; r < 4; r++) inv[r] = 1.f / l[r];

    f32x4 co[4];
#pragma unroll
    for (int n = 0; n < 4; n++) co[n] = (f32x4){0.f, 0.f, 0.f, 0.f};
    unsigned short* Pw = Ps + wv * (16 * PKW);

    for (int vc = 0; vc < 2; vc++) {
        __syncthreads();
#pragma unroll
        for (int it = 0; it < 4; it++) {
            int f = it * 512 + tid;
            load_lds16(vp + vc * 16384 + f * 8, KV + f * 8);
        }
        __syncthreads();
        for (int cs = 0; cs < 4; cs++) {
            int c = vc * 4 + cs;
#pragma unroll
            for (int tt = 0; tt < 4; tt++)
#pragma unroll
                for (int r = 0; r < 4; r++)
                    Pw[(quad * 4 + r) * PKW + tt * 16 + fm] = f2bf(sc[c * 4 + tt][r]);
#pragma unroll
            for (int s = 0; s < 2; s++) {
                s16x8 ap = *(const s16x8*)&Pw[fm * PKW + s * 32 + quad * 8];
#pragma unroll
                for (int n = 0; n < 4; n++) {
                    s16x8 bv = *(const s16x8*)&KV[(cs * 8 + s * 4 + quad) * 512 + (n * 16 + fm) * 8];
                    co[n] = __builtin_amdgcn_mfma_f32_16x16x32_bf16(ap, bv, co[n], 0, 0, 0);
                }
            }
        }
    }

    const size_t obase = (size_t)(b * LMAX + q0) * D + h * DH;
#pragma unroll
    for (int n = 0; n < 4; n++)
#pragma unroll
        for (int r = 0; r < 4; r++)
            ctx[obase + (size_t)(quad * 4 + r) * D + n * 16 + fm] = f2bf(co[n][r] * inv[r]);
}

// ---------------------------------------------------------------------------
// Barrier-free fused (partial-sum + bias) + LayerNorm + segment-mean.
// Row value = f1a + f1b + attn_out_b. Grid (B, 8), 4 waves/block, 8 rows/wave.
__global__ __launch_bounds__(256) void lnmean_kernel(const unsigned short* __restrict__ f1a,
                                                     const unsigned short* __restrict__ f1b,
                                                     const float* __restrict__ bo,
                                                     const float* __restrict__ g,
                                                     const float* __restrict__ bb,
                                                     const int* __restrict__ counts,
                                                     float* __restrict__ msum) {
    int b = blockIdx.x;
    int t = threadIdx.x;
    int wv = t >> 6, lane = t & 63;
    int cnt = counts[b];
    int s0 = blockIdx.y * 32 + wv * 8;
    int s1 = min(cnt, s0 + 8);

    float4 gg[4], bv[4], bo4[4];
#pragma unroll
    for (int c = 0; c < 4; c++) {
        gg[c]  = *(const float4*)&g[c * 256 + lane * 4];
        bv[c]  = *(const float4*)&bb[c * 256 + lane * 4];
        bo4[c] = *(const float4*)&bo[c * 256 + lane * 4];
    }
    float4 acc[4];
#pragma unroll
    for (int c = 0; c < 4; c++) acc[c] = (float4){0.f, 0.f, 0.f, 0.f};

    for (int s = s0; s < s1; s++) {
        size_t rbase = ((size_t)(b * LMAX + s)) * D;
        float4 v[4];
        float sm = 0.f, ss = 0.f;
#pragma unroll
        for (int c = 0; c < 4; c++) {
            ushort4 ua = *(const ushort4*)&f1a[rbase + c * 256 + lane * 4];
            ushort4 ub = *(const ushort4*)&f1b[rbase + c * 256 + lane * 4];
            v[c].x = bf2f(ua.x) + bf2f(ub.x) + bo4[c].x;
            v[c].y = bf2f(ua.y) + bf2f(ub.y) + bo4[c].y;
            v[c].z = bf2f(ua.z) + bf2f(ub.z) + bo4[c].z;
            v[c].w = bf2f(ua.w) + bf2f(ub.w) + bo4[c].w;
            sm += v[c].x + v[c].y + v[c].z + v[c].w;
            ss += v[c].x * v[c].x + v[c].y * v[c].y + v[c].z * v[c].z + v[c].w * v[c].w;
        }
#pragma unroll
        for (int o = 32; o; o >>= 1) { sm += __shfl_xor(sm, o); ss += __shfl_xor(ss, o); }
        float mu = sm * (1.f / D);
        float var = ss * (1.f / D) - mu * mu;
        float r = rsqrtf(var + LN_EPS);
#pragma unroll
        for (int c = 0; c < 4; c++) {
            acc[c].x += (v[c].x - mu) * r * gg[c].x + bv[c].x;
            acc[c].y += (v[c].y - mu) * r * gg[c].y + bv[c].y;
            acc[c].z += (v[c].z - mu) * r * gg[c].z + bv[c].z;
            acc[c].w += (v[c].w - mu) * r * gg[c].w + bv[c].w;
        }
    }
    float inv = 1.f / (float)max(cnt, 1);
#pragma unroll
    for (int c = 0; c < 4; c++) {
        int base = b * D + c * 256 + lane * 4;
        atomicAdd(&msum[base + 0], acc[c].x * inv);
        atomicAdd(&msum[base + 1], acc[c].y * inv);
        atomicAdd(&msum[base + 2], acc[c].z * inv);
        atomicAdd(&msum[base + 3], acc[c].w * inv);
    }
}

// Mini projection: out[b][n] = msum[b] . proj_w[n] + bias[n]  (fp32).
__global__ __launch_bounds__(256) void tproj_kernel(const float* __restrict__ msum,
                                                    const float* __restrict__ W,
                                                    const float* __restrict__ bias,
                                                    float* __restrict__ out) {
    int lane = threadIdx.x & 63;
    int n = blockIdx.x * 4 + (threadIdx.x >> 6);
    float4 wr[4];
#pragma unroll
    for (int i = 0; i < 4; i++)
        wr[i] = *(const float4*)&W[(size_t)n * D + i * 256 + lane * 4];
    float bn = bias[n];
    for (int b = 0; b < B; b++) {
        float s = 0.f;
#pragma unroll
        for (int i = 0; i < 4; i++) {
            float4 m4 = *(const float4*)&msum[(size_t)b * D + i * 256 + lane * 4];
            s += m4.x * wr[i].x + m4.y * wr[i].y + m4.z * wr[i].z + m4.w * wr[i].w;
        }
#pragma unroll
        for (int o = 32; o; o >>= 1) s += __shfl_xor(s, o);
        if (lane == 0) out[(size_t)b * D + n] = s + bn;
    }
}

// ---------------------------------------------------------------------------
extern "C" void kernel_launch(void* const* d_in, const int* in_sizes, int n_in,
                              void* d_out, int out_size, void* d_ws, size_t ws_size,
                              hipStream_t stream) {
    const float* struct_token = (const float*)d_in[0];
    const float* text_token   = (const float*)d_in[1];
    const float* in_proj_w    = (const float*)d_in[2];
    const float* in_proj_b    = (const float*)d_in[3];
    const float* attn_out_w   = (const float*)d_in[4];
    const float* attn_out_b   = (const float*)d_in[5];
    const float* ln_g         = (const float*)d_in[6];
    const float* ln_b         = (const float*)d_in[7];
    const float* proj_w       = (const float*)d_in[8];
    const float* proj_b       = (const float*)d_in[9];
    const int*   sb           = (const int*)d_in[10];
    float* out = (float*)d_out;

    const size_t MQ  = (size_t)B * LMAX;     // 4096
    const size_t MKV = (size_t)B * LT;       // 8192

    char* p = (char*)d_ws;
    unsigned short* padded_b = (unsigned short*)p;  p += MQ * D * 2;
    unsigned short* text_b   = (unsigned short*)p;  p += MKV * D * 2;
    unsigned short* wqkv_b   = (unsigned short*)p;  p += (size_t)3 * D * D * 2;
    unsigned short* wattn_b  = (unsigned short*)p;  p += (size_t)D * D * 2;
    unsigned short* qpack    = (unsigned short*)p;  p += MQ * D * 2;
    unsigned short* kpack    = (unsigned short*)p;  p += MKV * D * 2;
    unsigned short* vpack    = (unsigned short*)p;  p += MKV * D * 2;
    unsigned short* ctx_b    = (unsigned short*)p;  p += MQ * D * 2;
    unsigned short* f1a      = (unsigned short*)p;  p += MQ * D * 2;
    unsigned short* f1b      = (unsigned short*)p;  p += MQ * D * 2;
    float* msum = (float*)p;  p += (size_t)B * D * 4;
    int* counts = (int*)p;  p += B * 4;
    int* starts = (int*)p;  p += B * 4;

    hipMemsetAsync(msum, 0, (size_t)B * D * 4, stream);

    cast3_prep<<<6145, 256, 0, stream>>>(
        text_token, text_b, (int)(MKV * D),
        in_proj_w,  wqkv_b, 3 * D * D,
        attn_out_w, wattn_b, D * D,
        sb, counts, starts);

    scatter_full<<<dim3(LMAX, B), 256, 0, stream>>>(struct_token, counts, starts, padded_b);

    qkv_fused<<<1280, 256, 0, stream>>>(padded_b, text_b, wqkv_b, in_proj_b,
                                        qpack, kpack, vpack);

    attn_mfma<<<dim3(H, B, 2), 512, 0, stream>>>(qpack, kpack, vpack, ctx_b);

    // attn_out projection, split-K=2 -> two bf16 partial buffers
    gemm_bf2<<<512, 256, 0, stream>>>(ctx_b, wattn_b, f1a, f1b, D, D);

    lnmean_kernel<<<dim3(B, 8), 256, 0, stream>>>(f1a, f1b, attn_out_b, ln_g, ln_b, counts, msum);

    tproj_kernel<<<256, 256, 0, stream>>>(msum, proj_w, proj_b, out);
}